// Round 1
// baseline (2027.465 us; speedup 1.0000x reference)
//
#include <hip/hip_runtime.h>
#include <math.h>

// Problem constants
#define NT   197          // tokens
#define BB   256          // batch
#define CD   768          // channels
#define NHD  12           // heads
#define HD   64           // head dim
#define LTK  98           // kept tokens
#define NEWN 100          // L+2
#define M1   (NT*BB)      // 50432 rows
#define M2   (NEWN*BB)    // 25600 rows

typedef __attribute__((ext_vector_type(8))) short short8;
typedef __attribute__((ext_vector_type(4))) float float4v;

// ---------- bf16 helpers (avoid hip_bf16.h API) ----------
__device__ __forceinline__ short f2bf(float f) {
    unsigned int u = __float_as_uint(f);
    u = (u + 0x7fffu + ((u >> 16) & 1u)) >> 16;   // RNE
    return (short)u;
}

__device__ __forceinline__ void global_to_lds16(const short* g, short* l) {
    __builtin_amdgcn_global_load_lds(
        (__attribute__((address_space(1))) void*)(void*)g,
        (__attribute__((address_space(3))) void*)l, 16, 0, 0);
}

// ---------- fp32 -> bf16 convert ----------
__global__ __launch_bounds__(256) void cvt_bf16(const float* __restrict__ s,
                                                short* __restrict__ d, int n) {
    int i = blockIdx.x * 256 + threadIdx.x;
    if (i < n) d[i] = f2bf(s[i]);
}

// ---------- LayerNorm: fp32 in, bf16 out (+ optional stats for fp32 replay) ----------
__global__ __launch_bounds__(256)
void ln_fwd(const float* __restrict__ x, const float* __restrict__ g,
            const float* __restrict__ bb, short* __restrict__ ob,
            float2* __restrict__ stats) {
    int row = blockIdx.x * 4 + (threadIdx.x >> 6);
    int lane = threadIdx.x & 63;
    const float* xr = x + (size_t)row * CD;
    float v[12]; float s = 0.f;
#pragma unroll
    for (int i = 0; i < 12; i++) { v[i] = xr[lane + i * 64]; s += v[i]; }
#pragma unroll
    for (int o = 32; o; o >>= 1) s += __shfl_xor(s, o);
    float mu = s * (1.f / 768.f);
    float s2 = 0.f;
#pragma unroll
    for (int i = 0; i < 12; i++) { float d = v[i] - mu; s2 += d * d; }
#pragma unroll
    for (int o = 32; o; o >>= 1) s2 += __shfl_xor(s2, o);
    float rsig = rsqrtf(s2 * (1.f / 768.f) + 1e-5f);
    if (stats != nullptr && lane == 0) stats[row] = make_float2(mu, rsig);
#pragma unroll
    for (int i = 0; i < 12; i++) {
        int c = lane + i * 64;
        ob[(size_t)row * CD + c] = f2bf((v[i] - mu) * rsig * g[c] + bb[c]);
    }
}

// ---------- BT GEMM: out[m,n] = sum_k A[m,k]*W[n,k] (+epilogue) ----------
// EPI 0: bf16 out = acc + bias           (qkv)
// EPI 1: f32 out  = acc + bias + res[m,n] (out_proj -> x1, proj -> d_out)
// EPI 2: bf16 out = quickgelu(acc + bias) (fc)
template <int EPI>
__global__ __launch_bounds__(256)
void gemm_bt(const short* __restrict__ A, const short* __restrict__ Bw,
             const float* __restrict__ bias, const float* __restrict__ res,
             void* __restrict__ out, int M, int Nd, int K) {
    __shared__ short As[128 * 32];
    __shared__ short Bs[128 * 32];
    const int tid = threadIdx.x;
    const int m0 = blockIdx.x * 128, n0 = blockIdx.y * 128;
    const int wave = tid >> 6, lane = tid & 63;
    const int wm = wave >> 1, wn = wave & 1;

    float4v acc[4][4];
#pragma unroll
    for (int a = 0; a < 4; a++)
#pragma unroll
        for (int b = 0; b < 4; b++) acc[a][b] = (float4v){0.f, 0.f, 0.f, 0.f};

    const int r = lane & 15, q = lane >> 4;

    for (int k0 = 0; k0 < K; k0 += 32) {
        // --- stage A/B tiles via async global->LDS, chunk-XOR swizzled ---
#pragma unroll
        for (int i = 0; i < 2; i++) {
            int id = (wave * 2 + i) * 64 + lane;     // 0..511
            int row = id >> 2, cpos = id & 3;
            int csrc = cpos ^ ((row >> 1) & 3);
            global_to_lds16(A + (size_t)(m0 + row) * K + k0 + csrc * 8,
                            As + (wave * 2 + i) * 512);
            global_to_lds16(Bw + (size_t)(n0 + row) * K + k0 + csrc * 8,
                            Bs + (wave * 2 + i) * 512);
        }
        __syncthreads();
        short8 af[4], bf[4];
#pragma unroll
        for (int mi = 0; mi < 4; mi++) {
            int row = wm * 64 + mi * 16 + r;
            int cp = q ^ ((row >> 1) & 3);
            af[mi] = *(const short8*)(As + row * 32 + cp * 8);
        }
#pragma unroll
        for (int ni = 0; ni < 4; ni++) {
            int row = wn * 64 + ni * 16 + r;
            int cp = q ^ ((row >> 1) & 3);
            bf[ni] = *(const short8*)(Bs + row * 32 + cp * 8);
        }
#pragma unroll
        for (int mi = 0; mi < 4; mi++)
#pragma unroll
            for (int ni = 0; ni < 4; ni++)
                acc[mi][ni] = __builtin_amdgcn_mfma_f32_16x16x32_bf16(
                    af[mi], bf[ni], acc[mi][ni], 0, 0, 0);
        __syncthreads();
    }

    // --- epilogue ---
#pragma unroll
    for (int ni = 0; ni < 4; ni++) {
        int col = n0 + wn * 64 + ni * 16 + r;
        float bv = bias[col];
#pragma unroll
        for (int mi = 0; mi < 4; mi++) {
#pragma unroll
            for (int r2 = 0; r2 < 4; r2++) {
                int row = m0 + wm * 64 + mi * 16 + q * 4 + r2;
                size_t off = (size_t)row * Nd + col;
                float v = acc[mi][ni][r2] + bv;
                if (EPI == 0) {
                    ((short*)out)[off] = f2bf(v);
                } else if (EPI == 1) {
                    ((float*)out)[off] = v + res[off];
                } else {
                    float gel = v / (1.f + __expf(-1.702f * v));
                    ((short*)out)[off] = f2bf(gel);
                }
            }
        }
    }
}

// ---------- fused attention, one workgroup per (b,h), 7 waves ----------
__global__ __launch_bounds__(448)
void attn_kernel(const short* __restrict__ qkv, short* __restrict__ o) {
    __shared__ short Ks[224 * 72];      // [key][d], stride 72 (2-way banks = free)
    __shared__ short Vt[64 * 232];      // [d][key], stride 232
    __shared__ short Ps[7 * 16 * 232];  // per-wave P tile [16][232]

    const int b = blockIdx.x / NHD, h = blockIdx.x % NHD;
    const int tid = threadIdx.x;
    const int wave = tid >> 6, lane = tid & 63;

    // --- K into LDS (zero-pad keys 197..223) ---
#pragma unroll
    for (int i = 0; i < 4; i++) {
        int id = tid + 448 * i;          // 0..1791 = 224 rows * 8 chunks
        int n = id >> 3, ch = id & 7;
        uint4 val = {0u, 0u, 0u, 0u};
        if (n < NT)
            val = *(const uint4*)(qkv + ((size_t)(n * BB + b) * 2304 + 768 + h * 64 + ch * 8));
        *(uint4*)(&Ks[n * 72 + ch * 8]) = val;
    }
    // --- V transposed into LDS ---
#pragma unroll
    for (int rr = 0; rr < 8; rr++) {
        int p = (tid >> 5) + rr * 14;    // key pair 0..111
        int dl = tid & 31;
        int n0p = 2 * p;
#pragma unroll
        for (int di = 0; di < 2; di++) {
            int d = dl + 32 * di;
            unsigned int pack = 0;
            if (n0p < NT)
                pack |= (unsigned int)*(const unsigned short*)(qkv +
                    ((size_t)(n0p * BB + b) * 2304 + 1536 + h * 64 + d));
            if (n0p + 1 < NT)
                pack |= ((unsigned int)*(const unsigned short*)(qkv +
                    ((size_t)((n0p + 1) * BB + b) * 2304 + 1536 + h * 64 + d))) << 16;
            *(unsigned int*)(&Vt[d * 232 + n0p]) = pack;
        }
    }
    __syncthreads();

    short* Ps_w = Ps + wave * 16 * 232;
    const int cl = lane & 15, qg = lane >> 4;

    for (int rep = 0; rep < 2; rep++) {
        int qt = wave + rep * 7;         // query tile 0..13
        int q0 = qt * 16;
        // Q A-fragments straight from global
        int m = q0 + cl; int mrow = (m < NT) ? m : (NT - 1);
        short8 qf[2];
#pragma unroll
        for (int kk = 0; kk < 2; kk++)
            qf[kk] = *(const short8*)(qkv + ((size_t)(mrow * BB + b) * 2304 +
                                             h * 64 + kk * 32 + qg * 8));
        // S = Q K^T over 14 key tiles
        float4v sacc[14];
#pragma unroll
        for (int nt = 0; nt < 14; nt++) sacc[nt] = (float4v){0.f, 0.f, 0.f, 0.f};
#pragma unroll
        for (int kk = 0; kk < 2; kk++) {
#pragma unroll
            for (int nt = 0; nt < 14; nt++) {
                short8 kf = *(const short8*)(&Ks[(nt * 16 + cl) * 72 + kk * 32 + qg * 8]);
                sacc[nt] = __builtin_amdgcn_mfma_f32_16x16x32_bf16(qf[kk], kf, sacc[nt], 0, 0, 0);
            }
        }
        // mask invalid keys, row max
        float mx[4] = {-1e30f, -1e30f, -1e30f, -1e30f};
#pragma unroll
        for (int nt = 0; nt < 14; nt++) {
            int col = nt * 16 + cl;
            bool valid = col < NT;
#pragma unroll
            for (int r2 = 0; r2 < 4; r2++) {
                if (!valid) sacc[nt][r2] = -1e30f;
                mx[r2] = fmaxf(mx[r2], sacc[nt][r2]);
            }
        }
#pragma unroll
        for (int o2 = 1; o2 < 16; o2 <<= 1)
#pragma unroll
            for (int r2 = 0; r2 < 4; r2++) mx[r2] = fmaxf(mx[r2], __shfl_xor(mx[r2], o2));
        // exp + row sum (softmax(scale*s): exp(scale*(s-mx)))
        float sm[4] = {0.f, 0.f, 0.f, 0.f};
#pragma unroll
        for (int nt = 0; nt < 14; nt++)
#pragma unroll
            for (int r2 = 0; r2 < 4; r2++) {
                float pv = __expf((sacc[nt][r2] - mx[r2]) * 0.125f);
                sacc[nt][r2] = pv; sm[r2] += pv;
            }
#pragma unroll
        for (int o2 = 1; o2 < 16; o2 <<= 1)
#pragma unroll
            for (int r2 = 0; r2 < 4; r2++) sm[r2] += __shfl_xor(sm[r2], o2);
        float inv[4];
#pragma unroll
        for (int r2 = 0; r2 < 4; r2++) inv[r2] = 1.f / sm[r2];
        // write P to LDS (C-layout -> A-layout relayout)
#pragma unroll
        for (int nt = 0; nt < 14; nt++) {
            int col = nt * 16 + cl;
#pragma unroll
            for (int r2 = 0; r2 < 4; r2++)
                Ps_w[(qg * 4 + r2) * 232 + col] = f2bf(sacc[nt][r2] * inv[r2]);
        }
        __syncthreads();
        // O = P V
        float4v oacc[4];
#pragma unroll
        for (int dt = 0; dt < 4; dt++) oacc[dt] = (float4v){0.f, 0.f, 0.f, 0.f};
#pragma unroll
        for (int kk = 0; kk < 7; kk++) {
            short8 pf = *(const short8*)(&Ps_w[cl * 232 + kk * 32 + qg * 8]);
#pragma unroll
            for (int dt = 0; dt < 4; dt++) {
                short8 vf = *(const short8*)(&Vt[(dt * 16 + cl) * 232 + kk * 32 + qg * 8]);
                oacc[dt] = __builtin_amdgcn_mfma_f32_16x16x32_bf16(pf, vf, oacc[dt], 0, 0, 0);
            }
        }
#pragma unroll
        for (int dt = 0; dt < 4; dt++)
#pragma unroll
            for (int r2 = 0; r2 < 4; r2++) {
                int qrow = q0 + qg * 4 + r2;
                if (qrow < NT)
                    o[((size_t)qrow * BB + b) * CD + h * 64 + dt * 16 + cl] = f2bf(oacc[dt][r2]);
            }
        __syncthreads();
    }
}

// ---------- fp32 ranking path: u[b,h,c] = sum_d qcls[b,h*64+d] * Wk[h*64+d, c] ----------
__global__ __launch_bounds__(256)
void u_kernel(const float* __restrict__ x, const float2* __restrict__ stats,
              const float* __restrict__ g, const float* __restrict__ bln,
              const float* __restrict__ W, const float* __restrict__ pb,
              float* __restrict__ u, float* __restrict__ tq) {
    int b = blockIdx.x;
    __shared__ float lncls[CD];
    __shared__ float qc[CD];
    float2 st = stats[b];  // row of token 0 = b
    for (int c = threadIdx.x; c < CD; c += 256)
        lncls[c] = (x[(size_t)b * CD + c] - st.x) * st.y * g[c] + bln[c];
    __syncthreads();
    for (int d = threadIdx.x; d < CD; d += 256) {
        const float* wr = W + (size_t)d * CD;
        float acc = 0.f;
        for (int c = 0; c < CD; c++) acc += wr[c] * lncls[c];
        qc[d] = acc + pb[d];
    }
    __syncthreads();
    for (int t = threadIdx.x; t < NHD * CD; t += 256) {
        int h = t / CD, c = t % CD;
        const float* wk = W + (size_t)(CD + h * 64) * CD + c;
        float acc = 0.f;
        for (int d = 0; d < 64; d++) acc += qc[h * 64 + d] * wk[(size_t)d * CD];
        u[((size_t)b * NHD + h) * CD + c] = acc;
    }
    if (threadIdx.x < NHD) {
        int h = threadIdx.x; float acc = 0.f;
        for (int d = 0; d < 64; d++) acc += qc[h * 64 + d] * pb[CD + h * 64 + d];
        tq[b * NHD + h] = acc;
    }
}

// ---------- fp32 CLS scores: scores[b,h,n] = (u . ln1[n,b]) + tq, scaled ----------
__global__ __launch_bounds__(256)
void scores_kernel(const float* __restrict__ x, const float2* __restrict__ stats,
                   const float* __restrict__ g, const float* __restrict__ bln,
                   const float* __restrict__ u, const float* __restrict__ tq,
                   float* __restrict__ scores) {
    int bi = blockIdx.x; int b = bi / NT, n = bi % NT;
    __shared__ float ln[CD];
    int row = n * BB + b;
    float2 st = stats[row];
    for (int c = threadIdx.x; c < CD; c += 256)
        ln[c] = (x[(size_t)row * CD + c] - st.x) * st.y * g[c] + bln[c];
    __syncthreads();
    int wave = threadIdx.x >> 6, lane = threadIdx.x & 63;
    for (int h = wave; h < NHD; h += 4) {
        const float* ub = u + ((size_t)b * NHD + h) * CD;
        float acc = 0.f;
#pragma unroll
        for (int i = 0; i < 12; i++) acc += ub[lane + i * 64] * ln[lane + i * 64];
#pragma unroll
        for (int o2 = 32; o2; o2 >>= 1) acc += __shfl_xor(acc, o2);
        if (lane == 0)
            scores[((size_t)b * NHD + h) * NT + n] = (acc + tq[b * NHD + h]) * 0.125f;
    }
}

// ---------- softmax over 197 + head average -> cls_attn[b,196] ----------
__global__ __launch_bounds__(256)
void softmax_avg(const float* __restrict__ scores, float* __restrict__ cls_attn) {
    int b = blockIdx.x;
    __shared__ float p[NHD][NT];
    int wave = threadIdx.x >> 6, lane = threadIdx.x & 63;
    for (int h = wave; h < NHD; h += 4) {
        const float* s = scores + ((size_t)b * NHD + h) * NT;
        float v[4]; float mx = -1e30f;
#pragma unroll
        for (int i = 0; i < 4; i++) {
            int n = lane + i * 64;
            v[i] = (n < NT) ? s[n] : -1e30f;
            mx = fmaxf(mx, v[i]);
        }
#pragma unroll
        for (int o2 = 32; o2; o2 >>= 1) mx = fmaxf(mx, __shfl_xor(mx, o2));
        float sum = 0.f;
#pragma unroll
        for (int i = 0; i < 4; i++) {
            int n = lane + i * 64;
            v[i] = (n < NT) ? __expf(v[i] - mx) : 0.f;
            sum += v[i];
        }
#pragma unroll
        for (int o2 = 32; o2; o2 >>= 1) sum += __shfl_xor(sum, o2);
        float inv = 1.f / sum;
#pragma unroll
        for (int i = 0; i < 4; i++) {
            int n = lane + i * 64;
            if (n < NT) p[h][n] = v[i] * inv;
        }
    }
    __syncthreads();
    for (int n = 1 + (int)threadIdx.x; n < NT; n += 256) {
        float a = 0.f;
#pragma unroll
        for (int h = 0; h < NHD; h++) a += p[h][n];
        cls_attn[(size_t)b * (NT - 1) + n - 1] = a * (1.f / 12.f);
    }
}

// ---------- top-k (desc, stable) + complement (asc) ----------
__global__ __launch_bounds__(256)
void topk_kernel(const float* __restrict__ cls_attn, int* __restrict__ idx,
                 int* __restrict__ cidx, float* __restrict__ cw) {
    int b = blockIdx.x, t = threadIdx.x;
    __shared__ float kv[256];
    __shared__ int ki[256];
    __shared__ int pos[256];
    __shared__ unsigned char mem[256];
    float myv = (t < NT - 1) ? cls_attn[(size_t)b * (NT - 1) + t] : -INFINITY;
    kv[t] = myv; ki[t] = t;
    __syncthreads();
    for (int k = 2; k <= 256; k <<= 1) {
        for (int j = k >> 1; j > 0; j >>= 1) {
            int ixj = t ^ j;
            if (ixj > t) {
                bool up = ((t & k) == 0);
                float va = kv[t], vb = kv[ixj];
                int ia = ki[t], ib = ki[ixj];
                bool beforeAB = (va > vb) || (va == vb && ia < ib);  // desc, stable
                bool sw = up ? !beforeAB : beforeAB;
                if (sw) { kv[t] = vb; kv[ixj] = va; ki[t] = ib; ki[ixj] = ia; }
            }
            __syncthreads();
        }
    }
    if (t < LTK) idx[(size_t)b * LTK + t] = ki[t];
    mem[t] = 0;
    __syncthreads();
    if (t < LTK) mem[ki[t]] = 1;
    __syncthreads();
    int f = (t < NT - 1) ? (1 - (int)mem[t]) : 0;
    pos[t] = f;
    __syncthreads();
    for (int o2 = 1; o2 < 256; o2 <<= 1) {
        int add = (t >= o2) ? pos[t - o2] : 0;
        __syncthreads();
        pos[t] += add;
        __syncthreads();
    }
    if (f) {
        int p = pos[t] - 1;                 // 0..97, ascending in t
        cidx[(size_t)b * LTK + p] = t;
        cw[(size_t)b * LTK + p] = myv;
    }
}

// ---------- assemble x_new (100,B,C) from x1 ----------
__global__ __launch_bounds__(256)
void assemble(const float* __restrict__ x1, const int* __restrict__ idx,
              const int* __restrict__ cidx, const float* __restrict__ cw,
              float* __restrict__ xnew) {
    int b = blockIdx.x;
    for (int c = threadIdx.x; c < CD; c += 256)
        xnew[(size_t)b * CD + c] = x1[(size_t)b * CD + c];  // row 0 (CLS)
    for (int j = 0; j < LTK; j++) {
        int ns = idx[b * LTK + j] + 1;
        for (int c = threadIdx.x; c < CD; c += 256)
            xnew[((size_t)(1 + j) * BB + b) * CD + c] = x1[((size_t)ns * BB + b) * CD + c];
    }
    float acc[3] = {0.f, 0.f, 0.f};
    for (int m = 0; m < LTK; m++) {
        int ns = cidx[b * LTK + m] + 1;
        float w = cw[b * LTK + m];
#pragma unroll
        for (int i = 0; i < 3; i++)
            acc[i] += w * x1[((size_t)ns * BB + b) * CD + threadIdx.x + i * 256];
    }
#pragma unroll
    for (int i = 0; i < 3; i++)
        xnew[((size_t)99 * BB + b) * CD + threadIdx.x + i * 256] = acc[i];
}

__global__ __launch_bounds__(256) void sentinel_fill(float* __restrict__ p, int n) {
    int i = blockIdx.x * 256 + threadIdx.x;
    if (i < n) p[i] = 12345.0f;
}

// ---------- workspace layout (aliased; total ~581.5 MiB) ----------
#define OFF_WQKVB 0ULL
#define OFF_WOB   3538944ULL
#define OFF_WFCB  4718592ULL
#define OFF_WPRB  9437184ULL
#define OFF_STATS 14155776ULL
#define OFF_LN1   14559232ULL            /* bf16; O aliases this after qkv-GEMM */
#define OFF_O     OFF_LN1
#define OFF_QKV   92022784ULL            /* bf16; H aliases this after attn */
#define OFF_H     OFF_QKV
#define OFF_X1    324413440ULL
#define OFF_U     479340544ULL
#define OFF_TQ    488777728ULL
#define OFF_SC    488790016ULL
#define OFF_CA    491210752ULL
#define OFF_IDX   491411456ULL
#define OFF_CIDX  491511808ULL
#define OFF_CW    491612160ULL
#define OFF_XNEW  491712512ULL
#define OFF_LN2   570355712ULL
#define WS_NEED   609677312ULL

extern "C" void kernel_launch(void* const* d_in, const int* in_sizes, int n_in,
                              void* d_out, int out_size, void* d_ws, size_t ws_size,
                              hipStream_t stream) {
    const float* x      = (const float*)d_in[0];
    const float* ln1_g  = (const float*)d_in[1];
    const float* ln1_b  = (const float*)d_in[2];
    const float* w_qkv  = (const float*)d_in[3];
    const float* b_qkv  = (const float*)d_in[4];
    const float* w_o    = (const float*)d_in[5];
    const float* b_o    = (const float*)d_in[6];
    const float* ln2_g  = (const float*)d_in[7];
    const float* ln2_b  = (const float*)d_in[8];
    const float* w_fc   = (const float*)d_in[9];
    const float* b_fc   = (const float*)d_in[10];
    const float* w_proj = (const float*)d_in[11];
    const float* b_proj = (const float*)d_in[12];

    if (ws_size < WS_NEED) {  // clear sentinel signal: absmax ~= 12345
        sentinel_fill<<<(out_size + 255) / 256, 256, 0, stream>>>((float*)d_out, out_size);
        return;
    }

    char* ws = (char*)d_ws;
    short*  W_QKVB = (short*)(ws + OFF_WQKVB);
    short*  W_OB   = (short*)(ws + OFF_WOB);
    short*  W_FCB  = (short*)(ws + OFF_WFCB);
    short*  W_PRB  = (short*)(ws + OFF_WPRB);
    float2* STATS  = (float2*)(ws + OFF_STATS);
    short*  LN1    = (short*)(ws + OFF_LN1);
    short*  O      = (short*)(ws + OFF_O);
    short*  QKV    = (short*)(ws + OFF_QKV);
    short*  H      = (short*)(ws + OFF_H);
    float*  X1     = (float*)(ws + OFF_X1);
    float*  U      = (float*)(ws + OFF_U);
    float*  TQ     = (float*)(ws + OFF_TQ);
    float*  SC     = (float*)(ws + OFF_SC);
    float*  CA     = (float*)(ws + OFF_CA);
    int*    IDX    = (int*)(ws + OFF_IDX);
    int*    CIDX   = (int*)(ws + OFF_CIDX);
    float*  CW     = (float*)(ws + OFF_CW);
    float*  XNEW   = (float*)(ws + OFF_XNEW);
    short*  LN2    = (short*)(ws + OFF_LN2);

    // weights -> bf16
    cvt_bf16<<<(2304 * 768 + 255) / 256, 256, 0, stream>>>(w_qkv, W_QKVB, 2304 * 768);
    cvt_bf16<<<(768 * 768 + 255) / 256, 256, 0, stream>>>(w_o, W_OB, 768 * 768);
    cvt_bf16<<<(3072 * 768 + 255) / 256, 256, 0, stream>>>(w_fc, W_FCB, 3072 * 768);
    cvt_bf16<<<(768 * 3072 + 255) / 256, 256, 0, stream>>>(w_proj, W_PRB, 768 * 3072);

    // LN1 (bf16 out + stats for fp32 ranking replay)
    ln_fwd<<<M1 / 4, 256, 0, stream>>>(x, ln1_g, ln1_b, LN1, STATS);

    // qkv GEMM (bf16)
    gemm_bt<0><<<dim3(M1 / 128, 2304 / 128), 256, 0, stream>>>(
        LN1, W_QKVB, b_qkv, nullptr, QKV, M1, 2304, 768);

    // fused attention -> O (bf16)
    attn_kernel<<<BB * NHD, 448, 0, stream>>>(QKV, O);

    // fp32 ranking path
    u_kernel<<<BB, 256, 0, stream>>>(x, STATS, ln1_g, ln1_b, w_qkv, b_qkv, U, TQ);
    scores_kernel<<<BB * NT, 256, 0, stream>>>(x, STATS, ln1_g, ln1_b, U, TQ, SC);
    softmax_avg<<<BB, 256, 0, stream>>>(SC, CA);
    topk_kernel<<<BB, 256, 0, stream>>>(CA, IDX, CIDX, CW);

    // out_proj GEMM + residual -> x1 (fp32)
    gemm_bt<1><<<dim3(M1 / 128, 768 / 128), 256, 0, stream>>>(
        O, W_OB, b_o, x, X1, M1, 768, 768);

    // token select/merge -> x_new (fp32)
    assemble<<<BB, 256, 0, stream>>>(X1, IDX, CIDX, CW, XNEW);

    // LN2 -> bf16
    ln_fwd<<<M2 / 4, 256, 0, stream>>>(XNEW, ln2_g, ln2_b, LN2, nullptr);

    // fc GEMM + quickGELU -> H (bf16)
    gemm_bt<2><<<dim3(M2 / 128, 3072 / 128), 256, 0, stream>>>(
        LN2, W_FCB, b_fc, nullptr, H, M2, 3072, 768);

    // proj GEMM + bias + residual -> d_out (fp32)
    gemm_bt<1><<<dim3(M2 / 128, 768 / 128), 256, 0, stream>>>(
        H, W_PRB, b_proj, XNEW, (float*)d_out, M2, 768, 3072);
}

// Round 2
// 1966.242 us; speedup vs baseline: 1.0311x; 1.0311x over previous
//
#include <hip/hip_runtime.h>
#include <math.h>

// Problem constants
#define NT   197          // tokens
#define BB   256          // batch
#define CD   768          // channels
#define NHD  12           // heads
#define HD   64           // head dim
#define LTK  98           // kept tokens
#define NEWN 100          // L+2
#define M1   (NT*BB)      // 50432 rows
#define M2   (NEWN*BB)    // 25600 rows

typedef __attribute__((ext_vector_type(8))) short short8;
typedef __attribute__((ext_vector_type(4))) float float4v;

// ---------- bf16 helpers (avoid hip_bf16.h API) ----------
__device__ __forceinline__ short f2bf(float f) {
    unsigned int u = __float_as_uint(f);
    u = (u + 0x7fffu + ((u >> 16) & 1u)) >> 16;   // RNE
    return (short)u;
}

__device__ __forceinline__ void global_to_lds16(const short* g, short* l) {
    __builtin_amdgcn_global_load_lds(
        (__attribute__((address_space(1))) void*)(void*)g,
        (__attribute__((address_space(3))) void*)l, 16, 0, 0);
}

// ---------- fp32 -> bf16 convert ----------
__global__ __launch_bounds__(256) void cvt_bf16(const float* __restrict__ s,
                                                short* __restrict__ d, int n) {
    int i = blockIdx.x * 256 + threadIdx.x;
    if (i < n) d[i] = f2bf(s[i]);
}

// ---------- LayerNorm: fp32 in, bf16 out (+ optional stats for fp32 replay) ----------
__global__ __launch_bounds__(256)
void ln_fwd(const float* __restrict__ x, const float* __restrict__ g,
            const float* __restrict__ bb, short* __restrict__ ob,
            float2* __restrict__ stats) {
    int row = blockIdx.x * 4 + (threadIdx.x >> 6);
    int lane = threadIdx.x & 63;
    const float* xr = x + (size_t)row * CD;
    float v[12]; float s = 0.f;
#pragma unroll
    for (int i = 0; i < 12; i++) { v[i] = xr[lane + i * 64]; s += v[i]; }
#pragma unroll
    for (int o = 32; o; o >>= 1) s += __shfl_xor(s, o);
    float mu = s * (1.f / 768.f);
    float s2 = 0.f;
#pragma unroll
    for (int i = 0; i < 12; i++) { float d = v[i] - mu; s2 += d * d; }
#pragma unroll
    for (int o = 32; o; o >>= 1) s2 += __shfl_xor(s2, o);
    float rsig = rsqrtf(s2 * (1.f / 768.f) + 1e-5f);
    if (stats != nullptr && lane == 0) stats[row] = make_float2(mu, rsig);
#pragma unroll
    for (int i = 0; i < 12; i++) {
        int c = lane + i * 64;
        ob[(size_t)row * CD + c] = f2bf((v[i] - mu) * rsig * g[c] + bb[c]);
    }
}

// ---------- BT GEMM: out[m,n] = sum_k A[m,k]*W[n,k] (+epilogue) ----------
// Grid: 1-D, mTiles*nTiles blocks, supertile-swizzled: groups of GM m-tiles
// sweep all n-tiles consecutively so the A-slab stays hot in L2/L3.
// EPI 0: bf16 out = acc + bias           (qkv)
// EPI 1: f32 out  = acc + bias + res[m,n] (out_proj -> x1, proj -> d_out)
// EPI 2: bf16 out = quickgelu(acc + bias) (fc)
template <int EPI>
__global__ __launch_bounds__(256)
void gemm_bt(const short* __restrict__ A, const short* __restrict__ Bw,
             const float* __restrict__ bias, const float* __restrict__ res,
             void* __restrict__ out, int M, int Nd, int K) {
    __shared__ short As[128 * 32];
    __shared__ short Bs[128 * 32];
    const int tid = threadIdx.x;

    // --- supertile swizzle ---
    const int mTiles = M >> 7, nTiles = Nd >> 7;
    const int GM = 8;
    int per = GM * nTiles;
    int grp = blockIdx.x / per;
    int rem = blockIdx.x - grp * per;
    int gm = mTiles - grp * GM; if (gm > GM) gm = GM;
    int mt = grp * GM + rem % gm;
    int nt = rem / gm;
    const int m0 = mt * 128, n0 = nt * 128;

    const int wave = tid >> 6, lane = tid & 63;
    const int wm = wave >> 1, wn = wave & 1;

    float4v acc[4][4];
#pragma unroll
    for (int a = 0; a < 4; a++)
#pragma unroll
        for (int b = 0; b < 4; b++) acc[a][b] = (float4v){0.f, 0.f, 0.f, 0.f};

    const int r = lane & 15, q = lane >> 4;

    for (int k0 = 0; k0 < K; k0 += 32) {
        // --- stage A/B tiles via async global->LDS, chunk-XOR swizzled ---
#pragma unroll
        for (int i = 0; i < 2; i++) {
            int id = (wave * 2 + i) * 64 + lane;     // 0..511
            int row = id >> 2, cpos = id & 3;
            int csrc = cpos ^ ((row >> 1) & 3);
            global_to_lds16(A + (size_t)(m0 + row) * K + k0 + csrc * 8,
                            As + (wave * 2 + i) * 512);
            global_to_lds16(Bw + (size_t)(n0 + row) * K + k0 + csrc * 8,
                            Bs + (wave * 2 + i) * 512);
        }
        __syncthreads();
        short8 af[4], bf[4];
#pragma unroll
        for (int mi = 0; mi < 4; mi++) {
            int row = wm * 64 + mi * 16 + r;
            int cp = q ^ ((row >> 1) & 3);
            af[mi] = *(const short8*)(As + row * 32 + cp * 8);
        }
#pragma unroll
        for (int ni = 0; ni < 4; ni++) {
            int row = wn * 64 + ni * 16 + r;
            int cp = q ^ ((row >> 1) & 3);
            bf[ni] = *(const short8*)(Bs + row * 32 + cp * 8);
        }
#pragma unroll
        for (int mi = 0; mi < 4; mi++)
#pragma unroll
            for (int ni = 0; ni < 4; ni++)
                acc[mi][ni] = __builtin_amdgcn_mfma_f32_16x16x32_bf16(
                    af[mi], bf[ni], acc[mi][ni], 0, 0, 0);
        __syncthreads();
    }

    // --- epilogue ---
#pragma unroll
    for (int ni = 0; ni < 4; ni++) {
        int col = n0 + wn * 64 + ni * 16 + r;
        float bv = bias[col];
#pragma unroll
        for (int mi = 0; mi < 4; mi++) {
#pragma unroll
            for (int r2 = 0; r2 < 4; r2++) {
                int row = m0 + wm * 64 + mi * 16 + q * 4 + r2;
                size_t off = (size_t)row * Nd + col;
                float v = acc[mi][ni][r2] + bv;
                if (EPI == 0) {
                    ((short*)out)[off] = f2bf(v);
                } else if (EPI == 1) {
                    ((float*)out)[off] = v + res[off];
                } else {
                    float gel = v / (1.f + __expf(-1.702f * v));
                    ((short*)out)[off] = f2bf(gel);
                }
            }
        }
    }
}

// ---------- fused attention, one workgroup per (b,h), 7 waves ----------
__global__ __launch_bounds__(448)
void attn_kernel(const short* __restrict__ qkv, short* __restrict__ o) {
    __shared__ short Ks[224 * 72];      // [key][d], stride 72 (2-way banks = free)
    __shared__ short Vt[64 * 232];      // [d][key], stride 232
    __shared__ short Ps[7 * 16 * 232];  // per-wave P tile [16][232]

    const int b = blockIdx.x / NHD, h = blockIdx.x % NHD;
    const int tid = threadIdx.x;
    const int wave = tid >> 6, lane = tid & 63;

    // --- K into LDS (zero-pad keys 197..223) ---
#pragma unroll
    for (int i = 0; i < 4; i++) {
        int id = tid + 448 * i;          // 0..1791 = 224 rows * 8 chunks
        int n = id >> 3, ch = id & 7;
        uint4 val = {0u, 0u, 0u, 0u};
        if (n < NT)
            val = *(const uint4*)(qkv + ((size_t)(n * BB + b) * 2304 + 768 + h * 64 + ch * 8));
        *(uint4*)(&Ks[n * 72 + ch * 8]) = val;
    }
    // --- V transposed into LDS ---
#pragma unroll
    for (int rr = 0; rr < 8; rr++) {
        int p = (tid >> 5) + rr * 14;    // key pair 0..111
        int dl = tid & 31;
        int n0p = 2 * p;
#pragma unroll
        for (int di = 0; di < 2; di++) {
            int d = dl + 32 * di;
            unsigned int pack = 0;
            if (n0p < NT)
                pack |= (unsigned int)*(const unsigned short*)(qkv +
                    ((size_t)(n0p * BB + b) * 2304 + 1536 + h * 64 + d));
            if (n0p + 1 < NT)
                pack |= ((unsigned int)*(const unsigned short*)(qkv +
                    ((size_t)((n0p + 1) * BB + b) * 2304 + 1536 + h * 64 + d))) << 16;
            *(unsigned int*)(&Vt[d * 232 + n0p]) = pack;
        }
    }
    __syncthreads();

    short* Ps_w = Ps + wave * 16 * 232;
    const int cl = lane & 15, qg = lane >> 4;

    for (int rep = 0; rep < 2; rep++) {
        int qt = wave + rep * 7;         // query tile 0..13
        int q0 = qt * 16;
        // Q A-fragments straight from global
        int m = q0 + cl; int mrow = (m < NT) ? m : (NT - 1);
        short8 qf[2];
#pragma unroll
        for (int kk = 0; kk < 2; kk++)
            qf[kk] = *(const short8*)(qkv + ((size_t)(mrow * BB + b) * 2304 +
                                             h * 64 + kk * 32 + qg * 8));
        // S = Q K^T over 14 key tiles
        float4v sacc[14];
#pragma unroll
        for (int nt = 0; nt < 14; nt++) sacc[nt] = (float4v){0.f, 0.f, 0.f, 0.f};
#pragma unroll
        for (int kk = 0; kk < 2; kk++) {
#pragma unroll
            for (int nt = 0; nt < 14; nt++) {
                short8 kf = *(const short8*)(&Ks[(nt * 16 + cl) * 72 + kk * 32 + qg * 8]);
                sacc[nt] = __builtin_amdgcn_mfma_f32_16x16x32_bf16(qf[kk], kf, sacc[nt], 0, 0, 0);
            }
        }
        // mask invalid keys, row max
        float mx[4] = {-1e30f, -1e30f, -1e30f, -1e30f};
#pragma unroll
        for (int nt = 0; nt < 14; nt++) {
            int col = nt * 16 + cl;
            bool valid = col < NT;
#pragma unroll
            for (int r2 = 0; r2 < 4; r2++) {
                if (!valid) sacc[nt][r2] = -1e30f;
                mx[r2] = fmaxf(mx[r2], sacc[nt][r2]);
            }
        }
#pragma unroll
        for (int o2 = 1; o2 < 16; o2 <<= 1)
#pragma unroll
            for (int r2 = 0; r2 < 4; r2++) mx[r2] = fmaxf(mx[r2], __shfl_xor(mx[r2], o2));
        // exp + row sum (softmax(scale*s): exp(scale*(s-mx)))
        float sm[4] = {0.f, 0.f, 0.f, 0.f};
#pragma unroll
        for (int nt = 0; nt < 14; nt++)
#pragma unroll
            for (int r2 = 0; r2 < 4; r2++) {
                float pv = __expf((sacc[nt][r2] - mx[r2]) * 0.125f);
                sacc[nt][r2] = pv; sm[r2] += pv;
            }
#pragma unroll
        for (int o2 = 1; o2 < 16; o2 <<= 1)
#pragma unroll
            for (int r2 = 0; r2 < 4; r2++) sm[r2] += __shfl_xor(sm[r2], o2);
        float inv[4];
#pragma unroll
        for (int r2 = 0; r2 < 4; r2++) inv[r2] = 1.f / sm[r2];
        // write P to LDS (C-layout -> A-layout relayout)
#pragma unroll
        for (int nt = 0; nt < 14; nt++) {
            int col = nt * 16 + cl;
#pragma unroll
            for (int r2 = 0; r2 < 4; r2++)
                Ps_w[(qg * 4 + r2) * 232 + col] = f2bf(sacc[nt][r2] * inv[r2]);
        }
        __syncthreads();
        // O = P V
        float4v oacc[4];
#pragma unroll
        for (int dt = 0; dt < 4; dt++) oacc[dt] = (float4v){0.f, 0.f, 0.f, 0.f};
#pragma unroll
        for (int kk = 0; kk < 7; kk++) {
            short8 pf = *(const short8*)(&Ps_w[cl * 232 + kk * 32 + qg * 8]);
#pragma unroll
            for (int dt = 0; dt < 4; dt++) {
                short8 vf = *(const short8*)(&Vt[(dt * 16 + cl) * 232 + kk * 32 + qg * 8]);
                oacc[dt] = __builtin_amdgcn_mfma_f32_16x16x32_bf16(pf, vf, oacc[dt], 0, 0, 0);
            }
        }
#pragma unroll
        for (int dt = 0; dt < 4; dt++)
#pragma unroll
            for (int r2 = 0; r2 < 4; r2++) {
                int qrow = q0 + qg * 4 + r2;
                if (qrow < NT)
                    o[((size_t)qrow * BB + b) * CD + h * 64 + dt * 16 + cl] = f2bf(oacc[dt][r2]);
            }
        __syncthreads();
    }
}

// ---------- fp32 ranking path: u[b,h,c] = sum_d qcls[b,h*64+d] * Wk[h*64+d, c] ----------
__global__ __launch_bounds__(256)
void u_kernel(const float* __restrict__ x, const float2* __restrict__ stats,
              const float* __restrict__ g, const float* __restrict__ bln,
              const float* __restrict__ W, const float* __restrict__ pb,
              float* __restrict__ u, float* __restrict__ tq) {
    int b = blockIdx.x;
    __shared__ float lncls[CD];
    __shared__ float qc[CD];
    float2 st = stats[b];  // row of token 0 = b
    for (int c = threadIdx.x; c < CD; c += 256)
        lncls[c] = (x[(size_t)b * CD + c] - st.x) * st.y * g[c] + bln[c];
    __syncthreads();
    for (int d = threadIdx.x; d < CD; d += 256) {
        const float* wr = W + (size_t)d * CD;
        float acc = 0.f;
        for (int c = 0; c < CD; c++) acc += wr[c] * lncls[c];
        qc[d] = acc + pb[d];
    }
    __syncthreads();
    for (int t = threadIdx.x; t < NHD * CD; t += 256) {
        int h = t / CD, c = t % CD;
        const float* wk = W + (size_t)(CD + h * 64) * CD + c;
        float acc = 0.f;
        for (int d = 0; d < 64; d++) acc += qc[h * 64 + d] * wk[(size_t)d * CD];
        u[((size_t)b * NHD + h) * CD + c] = acc;
    }
    if (threadIdx.x < NHD) {
        int h = threadIdx.x; float acc = 0.f;
        for (int d = 0; d < 64; d++) acc += qc[h * 64 + d] * pb[CD + h * 64 + d];
        tq[b * NHD + h] = acc;
    }
}

// ---------- fp32 CLS scores: scores[b,h,n] = (u . ln1[n,b]) + tq, scaled ----------
__global__ __launch_bounds__(256)
void scores_kernel(const float* __restrict__ x, const float2* __restrict__ stats,
                   const float* __restrict__ g, const float* __restrict__ bln,
                   const float* __restrict__ u, const float* __restrict__ tq,
                   float* __restrict__ scores) {
    int bi = blockIdx.x; int b = bi / NT, n = bi % NT;
    __shared__ float ln[CD];
    int row = n * BB + b;
    float2 st = stats[row];
    for (int c = threadIdx.x; c < CD; c += 256)
        ln[c] = (x[(size_t)row * CD + c] - st.x) * st.y * g[c] + bln[c];
    __syncthreads();
    int wave = threadIdx.x >> 6, lane = threadIdx.x & 63;
    for (int h = wave; h < NHD; h += 4) {
        const float* ub = u + ((size_t)b * NHD + h) * CD;
        float acc = 0.f;
#pragma unroll
        for (int i = 0; i < 12; i++) acc += ub[lane + i * 64] * ln[lane + i * 64];
#pragma unroll
        for (int o2 = 32; o2; o2 >>= 1) acc += __shfl_xor(acc, o2);
        if (lane == 0)
            scores[((size_t)b * NHD + h) * NT + n] = (acc + tq[b * NHD + h]) * 0.125f;
    }
}

// ---------- softmax over 197 + head average -> cls_attn[b,196] ----------
__global__ __launch_bounds__(256)
void softmax_avg(const float* __restrict__ scores, float* __restrict__ cls_attn) {
    int b = blockIdx.x;
    __shared__ float p[NHD][NT];
    int wave = threadIdx.x >> 6, lane = threadIdx.x & 63;
    for (int h = wave; h < NHD; h += 4) {
        const float* s = scores + ((size_t)b * NHD + h) * NT;
        float v[4]; float mx = -1e30f;
#pragma unroll
        for (int i = 0; i < 4; i++) {
            int n = lane + i * 64;
            v[i] = (n < NT) ? s[n] : -1e30f;
            mx = fmaxf(mx, v[i]);
        }
#pragma unroll
        for (int o2 = 32; o2; o2 >>= 1) mx = fmaxf(mx, __shfl_xor(mx, o2));
        float sum = 0.f;
#pragma unroll
        for (int i = 0; i < 4; i++) {
            int n = lane + i * 64;
            v[i] = (n < NT) ? __expf(v[i] - mx) : 0.f;
            sum += v[i];
        }
#pragma unroll
        for (int o2 = 32; o2; o2 >>= 1) sum += __shfl_xor(sum, o2);
        float inv = 1.f / sum;
#pragma unroll
        for (int i = 0; i < 4; i++) {
            int n = lane + i * 64;
            if (n < NT) p[h][n] = v[i] * inv;
        }
    }
    __syncthreads();
    for (int n = 1 + (int)threadIdx.x; n < NT; n += 256) {
        float a = 0.f;
#pragma unroll
        for (int h = 0; h < NHD; h++) a += p[h][n];
        cls_attn[(size_t)b * (NT - 1) + n - 1] = a * (1.f / 12.f);
    }
}

// ---------- top-k (desc, stable) + complement (asc) ----------
__global__ __launch_bounds__(256)
void topk_kernel(const float* __restrict__ cls_attn, int* __restrict__ idx,
                 int* __restrict__ cidx, float* __restrict__ cw) {
    int b = blockIdx.x, t = threadIdx.x;
    __shared__ float kv[256];
    __shared__ int ki[256];
    __shared__ int pos[256];
    __shared__ unsigned char mem[256];
    float myv = (t < NT - 1) ? cls_attn[(size_t)b * (NT - 1) + t] : -INFINITY;
    kv[t] = myv; ki[t] = t;
    __syncthreads();
    for (int k = 2; k <= 256; k <<= 1) {
        for (int j = k >> 1; j > 0; j >>= 1) {
            int ixj = t ^ j;
            if (ixj > t) {
                bool up = ((t & k) == 0);
                float va = kv[t], vb = kv[ixj];
                int ia = ki[t], ib = ki[ixj];
                bool beforeAB = (va > vb) || (va == vb && ia < ib);  // desc, stable
                bool sw = up ? !beforeAB : beforeAB;
                if (sw) { kv[t] = vb; kv[ixj] = va; ki[t] = ib; ki[ixj] = ia; }
            }
            __syncthreads();
        }
    }
    if (t < LTK) idx[(size_t)b * LTK + t] = ki[t];
    mem[t] = 0;
    __syncthreads();
    if (t < LTK) mem[ki[t]] = 1;
    __syncthreads();
    int f = (t < NT - 1) ? (1 - (int)mem[t]) : 0;
    pos[t] = f;
    __syncthreads();
    for (int o2 = 1; o2 < 256; o2 <<= 1) {
        int add = (t >= o2) ? pos[t - o2] : 0;
        __syncthreads();
        pos[t] += add;
        __syncthreads();
    }
    if (f) {
        int p = pos[t] - 1;                 // 0..97, ascending in t
        cidx[(size_t)b * LTK + p] = t;
        cw[(size_t)b * LTK + p] = myv;
    }
}

// ---------- assemble x_new (100,B,C) from x1 ----------
__global__ __launch_bounds__(256)
void assemble(const float* __restrict__ x1, const int* __restrict__ idx,
              const int* __restrict__ cidx, const float* __restrict__ cw,
              float* __restrict__ xnew) {
    int b = blockIdx.x;
    for (int c = threadIdx.x; c < CD; c += 256)
        xnew[(size_t)b * CD + c] = x1[(size_t)b * CD + c];  // row 0 (CLS)
    for (int j = 0; j < LTK; j++) {
        int ns = idx[b * LTK + j] + 1;
        for (int c = threadIdx.x; c < CD; c += 256)
            xnew[((size_t)(1 + j) * BB + b) * CD + c] = x1[((size_t)ns * BB + b) * CD + c];
    }
    float acc[3] = {0.f, 0.f, 0.f};
    for (int m = 0; m < LTK; m++) {
        int ns = cidx[b * LTK + m] + 1;
        float w = cw[b * LTK + m];
#pragma unroll
        for (int i = 0; i < 3; i++)
            acc[i] += w * x1[((size_t)ns * BB + b) * CD + threadIdx.x + i * 256];
    }
#pragma unroll
    for (int i = 0; i < 3; i++)
        xnew[((size_t)99 * BB + b) * CD + threadIdx.x + i * 256] = acc[i];
}

__global__ __launch_bounds__(256) void sentinel_fill(float* __restrict__ p, int n) {
    int i = blockIdx.x * 256 + threadIdx.x;
    if (i < n) p[i] = 12345.0f;
}

// ---------- workspace layout (aliased; total ~581.5 MiB) ----------
#define OFF_WQKVB 0ULL
#define OFF_WOB   3538944ULL
#define OFF_WFCB  4718592ULL
#define OFF_WPRB  9437184ULL
#define OFF_STATS 14155776ULL
#define OFF_LN1   14559232ULL            /* bf16; O aliases this after qkv-GEMM */
#define OFF_O     OFF_LN1
#define OFF_QKV   92022784ULL            /* bf16; H aliases this after attn */
#define OFF_H     OFF_QKV
#define OFF_X1    324413440ULL
#define OFF_U     479340544ULL
#define OFF_TQ    488777728ULL
#define OFF_SC    488790016ULL
#define OFF_CA    491210752ULL
#define OFF_IDX   491411456ULL
#define OFF_CIDX  491511808ULL
#define OFF_CW    491612160ULL
#define OFF_XNEW  491712512ULL
#define OFF_LN2   570355712ULL
#define WS_NEED   609677312ULL

extern "C" void kernel_launch(void* const* d_in, const int* in_sizes, int n_in,
                              void* d_out, int out_size, void* d_ws, size_t ws_size,
                              hipStream_t stream) {
    const float* x      = (const float*)d_in[0];
    const float* ln1_g  = (const float*)d_in[1];
    const float* ln1_b  = (const float*)d_in[2];
    const float* w_qkv  = (const float*)d_in[3];
    const float* b_qkv  = (const float*)d_in[4];
    const float* w_o    = (const float*)d_in[5];
    const float* b_o    = (const float*)d_in[6];
    const float* ln2_g  = (const float*)d_in[7];
    const float* ln2_b  = (const float*)d_in[8];
    const float* w_fc   = (const float*)d_in[9];
    const float* b_fc   = (const float*)d_in[10];
    const float* w_proj = (const float*)d_in[11];
    const float* b_proj = (const float*)d_in[12];

    if (ws_size < WS_NEED) {  // clear sentinel signal: absmax ~= 12345
        sentinel_fill<<<(out_size + 255) / 256, 256, 0, stream>>>((float*)d_out, out_size);
        return;
    }

    char* ws = (char*)d_ws;
    short*  W_QKVB = (short*)(ws + OFF_WQKVB);
    short*  W_OB   = (short*)(ws + OFF_WOB);
    short*  W_FCB  = (short*)(ws + OFF_WFCB);
    short*  W_PRB  = (short*)(ws + OFF_WPRB);
    float2* STATS  = (float2*)(ws + OFF_STATS);
    short*  LN1    = (short*)(ws + OFF_LN1);
    short*  O      = (short*)(ws + OFF_O);
    short*  QKV    = (short*)(ws + OFF_QKV);
    short*  H      = (short*)(ws + OFF_H);
    float*  X1     = (float*)(ws + OFF_X1);
    float*  U      = (float*)(ws + OFF_U);
    float*  TQ     = (float*)(ws + OFF_TQ);
    float*  SC     = (float*)(ws + OFF_SC);
    float*  CA     = (float*)(ws + OFF_CA);
    int*    IDX    = (int*)(ws + OFF_IDX);
    int*    CIDX   = (int*)(ws + OFF_CIDX);
    float*  CW     = (float*)(ws + OFF_CW);
    float*  XNEW   = (float*)(ws + OFF_XNEW);
    short*  LN2    = (short*)(ws + OFF_LN2);

    // weights -> bf16
    cvt_bf16<<<(2304 * 768 + 255) / 256, 256, 0, stream>>>(w_qkv, W_QKVB, 2304 * 768);
    cvt_bf16<<<(768 * 768 + 255) / 256, 256, 0, stream>>>(w_o, W_OB, 768 * 768);
    cvt_bf16<<<(3072 * 768 + 255) / 256, 256, 0, stream>>>(w_fc, W_FCB, 3072 * 768);
    cvt_bf16<<<(768 * 3072 + 255) / 256, 256, 0, stream>>>(w_proj, W_PRB, 768 * 3072);

    // LN1 (bf16 out + stats for fp32 ranking replay)
    ln_fwd<<<M1 / 4, 256, 0, stream>>>(x, ln1_g, ln1_b, LN1, STATS);

    // qkv GEMM (bf16)
    gemm_bt<0><<<(M1 / 128) * (2304 / 128), 256, 0, stream>>>(
        LN1, W_QKVB, b_qkv, nullptr, QKV, M1, 2304, 768);

    // fused attention -> O (bf16)
    attn_kernel<<<BB * NHD, 448, 0, stream>>>(QKV, O);

    // fp32 ranking path
    u_kernel<<<BB, 256, 0, stream>>>(x, STATS, ln1_g, ln1_b, w_qkv, b_qkv, U, TQ);
    scores_kernel<<<BB * NT, 256, 0, stream>>>(x, STATS, ln1_g, ln1_b, U, TQ, SC);
    softmax_avg<<<BB, 256, 0, stream>>>(SC, CA);
    topk_kernel<<<BB, 256, 0, stream>>>(CA, IDX, CIDX, CW);

    // out_proj GEMM + residual -> x1 (fp32)
    gemm_bt<1><<<(M1 / 128) * (768 / 128), 256, 0, stream>>>(
        O, W_OB, b_o, x, X1, M1, 768, 768);

    // token select/merge -> x_new (fp32)
    assemble<<<BB, 256, 0, stream>>>(X1, IDX, CIDX, CW, XNEW);

    // LN2 -> bf16
    ln_fwd<<<M2 / 4, 256, 0, stream>>>(XNEW, ln2_g, ln2_b, LN2, nullptr);

    // fc GEMM + quickGELU -> H (bf16)
    gemm_bt<2><<<(M2 / 128) * (3072 / 128), 256, 0, stream>>>(
        LN2, W_FCB, b_fc, nullptr, H, M2, 3072, 768);

    // proj GEMM + bias + residual -> d_out (fp32)
    gemm_bt<1><<<(M2 / 128) * (768 / 128), 256, 0, stream>>>(
        H, W_PRB, b_proj, XNEW, (float*)d_out, M2, 768, 3072);
}

// Round 3
// 1862.719 us; speedup vs baseline: 1.0884x; 1.0556x over previous
//
#include <hip/hip_runtime.h>
#include <math.h>

// Problem constants
#define NT   197          // tokens
#define BB   256          // batch
#define CD   768          // channels
#define NHD  12           // heads
#define HD   64           // head dim
#define LTK  98           // kept tokens
#define NEWN 100          // L+2
#define M1   (NT*BB)      // 50432 rows
#define M2   (NEWN*BB)    // 25600 rows

typedef __attribute__((ext_vector_type(8))) short short8;
typedef __attribute__((ext_vector_type(4))) float float4v;

// ---------- bf16 helpers ----------
__device__ __forceinline__ short f2bf(float f) {
    unsigned int u = __float_as_uint(f);
    u = (u + 0x7fffu + ((u >> 16) & 1u)) >> 16;   // RNE
    return (short)u;
}

__device__ __forceinline__ void global_to_lds16(const short* g, short* l) {
    __builtin_amdgcn_global_load_lds(
        (__attribute__((address_space(1))) void*)(void*)g,
        (__attribute__((address_space(3))) void*)l, 16, 0, 0);
}

// ---------- fp32 -> bf16 convert ----------
__global__ __launch_bounds__(256) void cvt_bf16(const float* __restrict__ s,
                                                short* __restrict__ d, int n) {
    int i = blockIdx.x * 256 + threadIdx.x;
    if (i < n) d[i] = f2bf(s[i]);
}

// ---------- LayerNorm: fp32 in, bf16 out (+ optional stats) ----------
__global__ __launch_bounds__(256)
void ln_fwd(const float* __restrict__ x, const float* __restrict__ g,
            const float* __restrict__ bb, short* __restrict__ ob,
            float2* __restrict__ stats) {
    int row = blockIdx.x * 4 + (threadIdx.x >> 6);
    int lane = threadIdx.x & 63;
    const float* xr = x + (size_t)row * CD;
    float v[12]; float s = 0.f;
#pragma unroll
    for (int i = 0; i < 12; i++) { v[i] = xr[lane + i * 64]; s += v[i]; }
#pragma unroll
    for (int o = 32; o; o >>= 1) s += __shfl_xor(s, o);
    float mu = s * (1.f / 768.f);
    float s2 = 0.f;
#pragma unroll
    for (int i = 0; i < 12; i++) { float d = v[i] - mu; s2 += d * d; }
#pragma unroll
    for (int o = 32; o; o >>= 1) s2 += __shfl_xor(s2, o);
    float rsig = rsqrtf(s2 * (1.f / 768.f) + 1e-5f);
    if (stats != nullptr && lane == 0) stats[row] = make_float2(mu, rsig);
#pragma unroll
    for (int i = 0; i < 12; i++) {
        int c = lane + i * 64;
        ob[(size_t)row * CD + c] = f2bf((v[i] - mu) * rsig * g[c] + bb[c]);
    }
}

// ---------- BT GEMM: 256x128 tile, 512 thr / 8 waves, supertile-swizzled ----------
// out[m,n] = sum_k A[m,k]*W[n,k] (+epilogue)
// EPI 0: bf16 out = acc + bias            (qkv)
// EPI 1: f32 out  = acc + bias + res[m,n] (out_proj -> x1, proj -> d_out)
// EPI 2: bf16 out = quickgelu(acc + bias) (fc)
template <int EPI>
__global__ __launch_bounds__(512)
void gemm_bt(const short* __restrict__ A, const short* __restrict__ Bw,
             const float* __restrict__ bias, const float* __restrict__ res,
             void* __restrict__ out, int M, int Nd, int K) {
    __shared__ short As[256 * 32];
    __shared__ short Bs[128 * 32];
    const int tid = threadIdx.x;

    // --- supertile swizzle: groups of GM m-tiles sweep all n-tiles ---
    const int mTiles = M >> 8, nTiles = Nd >> 7;
    const int GM = 8;
    int per = GM * nTiles;
    int grp = blockIdx.x / per;
    int rem = blockIdx.x - grp * per;
    int gm = mTiles - grp * GM; if (gm > GM) gm = GM;
    int mt = grp * GM + rem % gm;
    int nt = rem / gm;
    const int m0 = mt * 256, n0 = nt * 128;

    const int wave = tid >> 6, lane = tid & 63;
    const int wm = wave >> 1, wn = wave & 1;   // wm 0..3 (m 64-strips), wn 0..1

    float4v acc[4][4];
#pragma unroll
    for (int a = 0; a < 4; a++)
#pragma unroll
        for (int b = 0; b < 4; b++) acc[a][b] = (float4v){0.f, 0.f, 0.f, 0.f};

    const int r = lane & 15, q = lane >> 4;

    for (int k0 = 0; k0 < K; k0 += 32) {
        // --- stage A (256x32) + B (128x32), chunk-XOR swizzled ---
#pragma unroll
        for (int i = 0; i < 2; i++) {
            int id = (wave * 2 + i) * 64 + lane;     // 0..1023
            int row = id >> 2, cpos = id & 3;
            int csrc = cpos ^ ((row >> 1) & 3);
            global_to_lds16(A + (size_t)(m0 + row) * K + k0 + csrc * 8,
                            As + (wave * 2 + i) * 512);
        }
        {
            int id = wave * 64 + lane;               // 0..511
            int row = id >> 2, cpos = id & 3;
            int csrc = cpos ^ ((row >> 1) & 3);
            global_to_lds16(Bw + (size_t)(n0 + row) * K + k0 + csrc * 8,
                            Bs + wave * 512);
        }
        __syncthreads();
        short8 af[4], bf[4];
#pragma unroll
        for (int mi = 0; mi < 4; mi++) {
            int row = wm * 64 + mi * 16 + r;
            int cp = q ^ ((row >> 1) & 3);
            af[mi] = *(const short8*)(As + row * 32 + cp * 8);
        }
#pragma unroll
        for (int ni = 0; ni < 4; ni++) {
            int row = wn * 64 + ni * 16 + r;
            int cp = q ^ ((row >> 1) & 3);
            bf[ni] = *(const short8*)(Bs + row * 32 + cp * 8);
        }
#pragma unroll
        for (int mi = 0; mi < 4; mi++)
#pragma unroll
            for (int ni = 0; ni < 4; ni++)
                acc[mi][ni] = __builtin_amdgcn_mfma_f32_16x16x32_bf16(
                    af[mi], bf[ni], acc[mi][ni], 0, 0, 0);
        __syncthreads();
    }

    // --- epilogue ---
#pragma unroll
    for (int ni = 0; ni < 4; ni++) {
        int col = n0 + wn * 64 + ni * 16 + r;
        float bv = bias[col];
#pragma unroll
        for (int mi = 0; mi < 4; mi++) {
#pragma unroll
            for (int r2 = 0; r2 < 4; r2++) {
                int row = m0 + wm * 64 + mi * 16 + q * 4 + r2;
                size_t off = (size_t)row * Nd + col;
                float v = acc[mi][ni][r2] + bv;
                if (EPI == 0) {
                    ((short*)out)[off] = f2bf(v);
                } else if (EPI == 1) {
                    ((float*)out)[off] = v + res[off];
                } else {
                    float gel = v / (1.f + __expf(-1.702f * v));
                    ((short*)out)[off] = f2bf(gel);
                }
            }
        }
    }
}

// ---------- fused attention, one workgroup per (b,h), 7 waves ----------
__global__ __launch_bounds__(448)
void attn_kernel(const short* __restrict__ qkv, short* __restrict__ o) {
    __shared__ short Ks[224 * 72];      // [key][d], stride 72
    __shared__ short Vt[64 * 232];      // [d][key], stride 232
    __shared__ short Ps[7 * 16 * 232];  // per-wave P tile [16][232]

    const int b = blockIdx.x / NHD, h = blockIdx.x % NHD;
    const int tid = threadIdx.x;
    const int wave = tid >> 6, lane = tid & 63;

#pragma unroll
    for (int i = 0; i < 4; i++) {
        int id = tid + 448 * i;          // 0..1791 = 224 rows * 8 chunks
        int n = id >> 3, ch = id & 7;
        uint4 val = {0u, 0u, 0u, 0u};
        if (n < NT)
            val = *(const uint4*)(qkv + ((size_t)(n * BB + b) * 2304 + 768 + h * 64 + ch * 8));
        *(uint4*)(&Ks[n * 72 + ch * 8]) = val;
    }
#pragma unroll
    for (int rr = 0; rr < 8; rr++) {
        int p = (tid >> 5) + rr * 14;    // key pair 0..111
        int dl = tid & 31;
        int n0p = 2 * p;
#pragma unroll
        for (int di = 0; di < 2; di++) {
            int d = dl + 32 * di;
            unsigned int pack = 0;
            if (n0p < NT)
                pack |= (unsigned int)*(const unsigned short*)(qkv +
                    ((size_t)(n0p * BB + b) * 2304 + 1536 + h * 64 + d));
            if (n0p + 1 < NT)
                pack |= ((unsigned int)*(const unsigned short*)(qkv +
                    ((size_t)((n0p + 1) * BB + b) * 2304 + 1536 + h * 64 + d))) << 16;
            *(unsigned int*)(&Vt[d * 232 + n0p]) = pack;
        }
    }
    __syncthreads();

    short* Ps_w = Ps + wave * 16 * 232;
    const int cl = lane & 15, qg = lane >> 4;

    for (int rep = 0; rep < 2; rep++) {
        int qt = wave + rep * 7;         // query tile 0..13
        int q0 = qt * 16;
        int m = q0 + cl; int mrow = (m < NT) ? m : (NT - 1);
        short8 qf[2];
#pragma unroll
        for (int kk = 0; kk < 2; kk++)
            qf[kk] = *(const short8*)(qkv + ((size_t)(mrow * BB + b) * 2304 +
                                             h * 64 + kk * 32 + qg * 8));
        float4v sacc[14];
#pragma unroll
        for (int nt = 0; nt < 14; nt++) sacc[nt] = (float4v){0.f, 0.f, 0.f, 0.f};
#pragma unroll
        for (int kk = 0; kk < 2; kk++) {
#pragma unroll
            for (int nt = 0; nt < 14; nt++) {
                short8 kf = *(const short8*)(&Ks[(nt * 16 + cl) * 72 + kk * 32 + qg * 8]);
                sacc[nt] = __builtin_amdgcn_mfma_f32_16x16x32_bf16(qf[kk], kf, sacc[nt], 0, 0, 0);
            }
        }
        float mx[4] = {-1e30f, -1e30f, -1e30f, -1e30f};
#pragma unroll
        for (int nt = 0; nt < 14; nt++) {
            int col = nt * 16 + cl;
            bool valid = col < NT;
#pragma unroll
            for (int r2 = 0; r2 < 4; r2++) {
                if (!valid) sacc[nt][r2] = -1e30f;
                mx[r2] = fmaxf(mx[r2], sacc[nt][r2]);
            }
        }
#pragma unroll
        for (int o2 = 1; o2 < 16; o2 <<= 1)
#pragma unroll
            for (int r2 = 0; r2 < 4; r2++) mx[r2] = fmaxf(mx[r2], __shfl_xor(mx[r2], o2));
        float sm[4] = {0.f, 0.f, 0.f, 0.f};
#pragma unroll
        for (int nt = 0; nt < 14; nt++)
#pragma unroll
            for (int r2 = 0; r2 < 4; r2++) {
                float pv = __expf((sacc[nt][r2] - mx[r2]) * 0.125f);
                sacc[nt][r2] = pv; sm[r2] += pv;
            }
#pragma unroll
        for (int o2 = 1; o2 < 16; o2 <<= 1)
#pragma unroll
            for (int r2 = 0; r2 < 4; r2++) sm[r2] += __shfl_xor(sm[r2], o2);
        float inv[4];
#pragma unroll
        for (int r2 = 0; r2 < 4; r2++) inv[r2] = 1.f / sm[r2];
#pragma unroll
        for (int nt = 0; nt < 14; nt++) {
            int col = nt * 16 + cl;
#pragma unroll
            for (int r2 = 0; r2 < 4; r2++)
                Ps_w[(qg * 4 + r2) * 232 + col] = f2bf(sacc[nt][r2] * inv[r2]);
        }
        __syncthreads();
        float4v oacc[4];
#pragma unroll
        for (int dt = 0; dt < 4; dt++) oacc[dt] = (float4v){0.f, 0.f, 0.f, 0.f};
#pragma unroll
        for (int kk = 0; kk < 7; kk++) {
            short8 pf = *(const short8*)(&Ps_w[cl * 232 + kk * 32 + qg * 8]);
#pragma unroll
            for (int dt = 0; dt < 4; dt++) {
                short8 vf = *(const short8*)(&Vt[(dt * 16 + cl) * 232 + kk * 32 + qg * 8]);
                oacc[dt] = __builtin_amdgcn_mfma_f32_16x16x32_bf16(pf, vf, oacc[dt], 0, 0, 0);
            }
        }
#pragma unroll
        for (int dt = 0; dt < 4; dt++)
#pragma unroll
            for (int r2 = 0; r2 < 4; r2++) {
                int qrow = q0 + qg * 4 + r2;
                if (qrow < NT)
                    o[((size_t)qrow * BB + b) * CD + h * 64 + dt * 16 + cl] = f2bf(oacc[dt][r2]);
            }
        __syncthreads();
    }
}

// ---------- fp32 ranking path ----------
__global__ __launch_bounds__(256)
void u_kernel(const float* __restrict__ x, const float2* __restrict__ stats,
              const float* __restrict__ g, const float* __restrict__ bln,
              const float* __restrict__ W, const float* __restrict__ pb,
              float* __restrict__ u, float* __restrict__ tq) {
    int b = blockIdx.x;
    __shared__ float lncls[CD];
    __shared__ float qc[CD];
    float2 st = stats[b];
    for (int c = threadIdx.x; c < CD; c += 256)
        lncls[c] = (x[(size_t)b * CD + c] - st.x) * st.y * g[c] + bln[c];
    __syncthreads();
    for (int d = threadIdx.x; d < CD; d += 256) {
        const float* wr = W + (size_t)d * CD;
        float acc = 0.f;
        for (int c = 0; c < CD; c++) acc += wr[c] * lncls[c];
        qc[d] = acc + pb[d];
    }
    __syncthreads();
    for (int t = threadIdx.x; t < NHD * CD; t += 256) {
        int h = t / CD, c = t % CD;
        const float* wk = W + (size_t)(CD + h * 64) * CD + c;
        float acc = 0.f;
        for (int d = 0; d < 64; d++) acc += qc[h * 64 + d] * wk[(size_t)d * CD];
        u[((size_t)b * NHD + h) * CD + c] = acc;
    }
    if (threadIdx.x < NHD) {
        int h = threadIdx.x; float acc = 0.f;
        for (int d = 0; d < 64; d++) acc += qc[h * 64 + d] * pb[CD + h * 64 + d];
        tq[b * NHD + h] = acc;
    }
}

__global__ __launch_bounds__(256)
void scores_kernel(const float* __restrict__ x, const float2* __restrict__ stats,
                   const float* __restrict__ g, const float* __restrict__ bln,
                   const float* __restrict__ u, const float* __restrict__ tq,
                   float* __restrict__ scores) {
    int bi = blockIdx.x; int b = bi / NT, n = bi % NT;
    __shared__ float ln[CD];
    int row = n * BB + b;
    float2 st = stats[row];
    for (int c = threadIdx.x; c < CD; c += 256)
        ln[c] = (x[(size_t)row * CD + c] - st.x) * st.y * g[c] + bln[c];
    __syncthreads();
    int wave = threadIdx.x >> 6, lane = threadIdx.x & 63;
    for (int h = wave; h < NHD; h += 4) {
        const float* ub = u + ((size_t)b * NHD + h) * CD;
        float acc = 0.f;
#pragma unroll
        for (int i = 0; i < 12; i++) acc += ub[lane + i * 64] * ln[lane + i * 64];
#pragma unroll
        for (int o2 = 32; o2; o2 >>= 1) acc += __shfl_xor(acc, o2);
        if (lane == 0)
            scores[((size_t)b * NHD + h) * NT + n] = (acc + tq[b * NHD + h]) * 0.125f;
    }
}

__global__ __launch_bounds__(256)
void softmax_avg(const float* __restrict__ scores, float* __restrict__ cls_attn) {
    int b = blockIdx.x;
    __shared__ float p[NHD][NT];
    int wave = threadIdx.x >> 6, lane = threadIdx.x & 63;
    for (int h = wave; h < NHD; h += 4) {
        const float* s = scores + ((size_t)b * NHD + h) * NT;
        float v[4]; float mx = -1e30f;
#pragma unroll
        for (int i = 0; i < 4; i++) {
            int n = lane + i * 64;
            v[i] = (n < NT) ? s[n] : -1e30f;
            mx = fmaxf(mx, v[i]);
        }
#pragma unroll
        for (int o2 = 32; o2; o2 >>= 1) mx = fmaxf(mx, __shfl_xor(mx, o2));
        float sum = 0.f;
#pragma unroll
        for (int i = 0; i < 4; i++) {
            int n = lane + i * 64;
            v[i] = (n < NT) ? __expf(v[i] - mx) : 0.f;
            sum += v[i];
        }
#pragma unroll
        for (int o2 = 32; o2; o2 >>= 1) sum += __shfl_xor(sum, o2);
        float inv = 1.f / sum;
#pragma unroll
        for (int i = 0; i < 4; i++) {
            int n = lane + i * 64;
            if (n < NT) p[h][n] = v[i] * inv;
        }
    }
    __syncthreads();
    for (int n = 1 + (int)threadIdx.x; n < NT; n += 256) {
        float a = 0.f;
#pragma unroll
        for (int h = 0; h < NHD; h++) a += p[h][n];
        cls_attn[(size_t)b * (NT - 1) + n - 1] = a * (1.f / 12.f);
    }
}

__global__ __launch_bounds__(256)
void topk_kernel(const float* __restrict__ cls_attn, int* __restrict__ idx,
                 int* __restrict__ cidx, float* __restrict__ cw) {
    int b = blockIdx.x, t = threadIdx.x;
    __shared__ float kv[256];
    __shared__ int ki[256];
    __shared__ int pos[256];
    __shared__ unsigned char mem[256];
    float myv = (t < NT - 1) ? cls_attn[(size_t)b * (NT - 1) + t] : -INFINITY;
    kv[t] = myv; ki[t] = t;
    __syncthreads();
    for (int k = 2; k <= 256; k <<= 1) {
        for (int j = k >> 1; j > 0; j >>= 1) {
            int ixj = t ^ j;
            if (ixj > t) {
                bool up = ((t & k) == 0);
                float va = kv[t], vb = kv[ixj];
                int ia = ki[t], ib = ki[ixj];
                bool beforeAB = (va > vb) || (va == vb && ia < ib);  // desc, stable
                bool sw = up ? !beforeAB : beforeAB;
                if (sw) { kv[t] = vb; kv[ixj] = va; ki[t] = ib; ki[ixj] = ia; }
            }
            __syncthreads();
        }
    }
    if (t < LTK) idx[(size_t)b * LTK + t] = ki[t];
    mem[t] = 0;
    __syncthreads();
    if (t < LTK) mem[ki[t]] = 1;
    __syncthreads();
    int f = (t < NT - 1) ? (1 - (int)mem[t]) : 0;
    pos[t] = f;
    __syncthreads();
    for (int o2 = 1; o2 < 256; o2 <<= 1) {
        int add = (t >= o2) ? pos[t - o2] : 0;
        __syncthreads();
        pos[t] += add;
        __syncthreads();
    }
    if (f) {
        int p = pos[t] - 1;
        cidx[(size_t)b * LTK + p] = t;
        cw[(size_t)b * LTK + p] = myv;
    }
}

__global__ __launch_bounds__(256)
void assemble(const float* __restrict__ x1, const int* __restrict__ idx,
              const int* __restrict__ cidx, const float* __restrict__ cw,
              float* __restrict__ xnew) {
    int b = blockIdx.x;
    for (int c = threadIdx.x; c < CD; c += 256)
        xnew[(size_t)b * CD + c] = x1[(size_t)b * CD + c];
    for (int j = 0; j < LTK; j++) {
        int ns = idx[b * LTK + j] + 1;
        for (int c = threadIdx.x; c < CD; c += 256)
            xnew[((size_t)(1 + j) * BB + b) * CD + c] = x1[((size_t)ns * BB + b) * CD + c];
    }
    float acc[3] = {0.f, 0.f, 0.f};
    for (int m = 0; m < LTK; m++) {
        int ns = cidx[b * LTK + m] + 1;
        float w = cw[b * LTK + m];
#pragma unroll
        for (int i = 0; i < 3; i++)
            acc[i] += w * x1[((size_t)ns * BB + b) * CD + threadIdx.x + i * 256];
    }
#pragma unroll
    for (int i = 0; i < 3; i++)
        xnew[((size_t)99 * BB + b) * CD + threadIdx.x + i * 256] = acc[i];
}

__global__ __launch_bounds__(256) void sentinel_fill(float* __restrict__ p, int n) {
    int i = blockIdx.x * 256 + threadIdx.x;
    if (i < n) p[i] = 12345.0f;
}

// ---------- workspace layout ----------
#define OFF_WQKVB 0ULL
#define OFF_WOB   3538944ULL
#define OFF_WFCB  4718592ULL
#define OFF_WPRB  9437184ULL
#define OFF_STATS 14155776ULL
#define OFF_LN1   14559232ULL            /* bf16; O aliases this after qkv-GEMM */
#define OFF_O     OFF_LN1
#define OFF_QKV   92022784ULL            /* bf16; H aliases this after attn */
#define OFF_H     OFF_QKV
#define OFF_X1    324413440ULL
#define OFF_U     479340544ULL
#define OFF_TQ    488777728ULL
#define OFF_SC    488790016ULL
#define OFF_CA    491210752ULL
#define OFF_IDX   491411456ULL
#define OFF_CIDX  491511808ULL
#define OFF_CW    491612160ULL
#define OFF_XNEW  491712512ULL
#define OFF_LN2   570355712ULL
#define WS_NEED   609677312ULL

extern "C" void kernel_launch(void* const* d_in, const int* in_sizes, int n_in,
                              void* d_out, int out_size, void* d_ws, size_t ws_size,
                              hipStream_t stream) {
    const float* x      = (const float*)d_in[0];
    const float* ln1_g  = (const float*)d_in[1];
    const float* ln1_b  = (const float*)d_in[2];
    const float* w_qkv  = (const float*)d_in[3];
    const float* b_qkv  = (const float*)d_in[4];
    const float* w_o    = (const float*)d_in[5];
    const float* b_o    = (const float*)d_in[6];
    const float* ln2_g  = (const float*)d_in[7];
    const float* ln2_b  = (const float*)d_in[8];
    const float* w_fc   = (const float*)d_in[9];
    const float* b_fc   = (const float*)d_in[10];
    const float* w_proj = (const float*)d_in[11];
    const float* b_proj = (const float*)d_in[12];

    if (ws_size < WS_NEED) {
        sentinel_fill<<<(out_size + 255) / 256, 256, 0, stream>>>((float*)d_out, out_size);
        return;
    }

    char* ws = (char*)d_ws;
    short*  W_QKVB = (short*)(ws + OFF_WQKVB);
    short*  W_OB   = (short*)(ws + OFF_WOB);
    short*  W_FCB  = (short*)(ws + OFF_WFCB);
    short*  W_PRB  = (short*)(ws + OFF_WPRB);
    float2* STATS  = (float2*)(ws + OFF_STATS);
    short*  LN1    = (short*)(ws + OFF_LN1);
    short*  O      = (short*)(ws + OFF_O);
    short*  QKV    = (short*)(ws + OFF_QKV);
    short*  H      = (short*)(ws + OFF_H);
    float*  X1     = (float*)(ws + OFF_X1);
    float*  U      = (float*)(ws + OFF_U);
    float*  TQ     = (float*)(ws + OFF_TQ);
    float*  SC     = (float*)(ws + OFF_SC);
    float*  CA     = (float*)(ws + OFF_CA);
    int*    IDX    = (int*)(ws + OFF_IDX);
    int*    CIDX   = (int*)(ws + OFF_CIDX);
    float*  CW     = (float*)(ws + OFF_CW);
    float*  XNEW   = (float*)(ws + OFF_XNEW);
    short*  LN2    = (short*)(ws + OFF_LN2);

    // weights -> bf16
    cvt_bf16<<<(2304 * 768 + 255) / 256, 256, 0, stream>>>(w_qkv, W_QKVB, 2304 * 768);
    cvt_bf16<<<(768 * 768 + 255) / 256, 256, 0, stream>>>(w_o, W_OB, 768 * 768);
    cvt_bf16<<<(3072 * 768 + 255) / 256, 256, 0, stream>>>(w_fc, W_FCB, 3072 * 768);
    cvt_bf16<<<(768 * 3072 + 255) / 256, 256, 0, stream>>>(w_proj, W_PRB, 768 * 3072);

    // LN1 (bf16 out + stats for fp32 ranking replay)
    ln_fwd<<<M1 / 4, 256, 0, stream>>>(x, ln1_g, ln1_b, LN1, STATS);

    // qkv GEMM (bf16): 197 m-tiles x 18 n-tiles
    gemm_bt<0><<<(M1 / 256) * (2304 / 128), 512, 0, stream>>>(
        LN1, W_QKVB, b_qkv, nullptr, QKV, M1, 2304, 768);

    // fused attention -> O (bf16)
    attn_kernel<<<BB * NHD, 448, 0, stream>>>(QKV, O);

    // fp32 ranking path
    u_kernel<<<BB, 256, 0, stream>>>(x, STATS, ln1_g, ln1_b, w_qkv, b_qkv, U, TQ);
    scores_kernel<<<BB * NT, 256, 0, stream>>>(x, STATS, ln1_g, ln1_b, U, TQ, SC);
    softmax_avg<<<BB, 256, 0, stream>>>(SC, CA);
    topk_kernel<<<BB, 256, 0, stream>>>(CA, IDX, CIDX, CW);

    // out_proj GEMM + residual -> x1 (fp32)
    gemm_bt<1><<<(M1 / 256) * (768 / 128), 512, 0, stream>>>(
        O, W_OB, b_o, x, X1, M1, 768, 768);

    // token select/merge -> x_new (fp32)
    assemble<<<BB, 256, 0, stream>>>(X1, IDX, CIDX, CW, XNEW);

    // LN2 -> bf16
    ln_fwd<<<M2 / 4, 256, 0, stream>>>(XNEW, ln2_g, ln2_b, LN2, nullptr);

    // fc GEMM + quickGELU -> H (bf16)
    gemm_bt<2><<<(M2 / 256) * (3072 / 128), 512, 0, stream>>>(
        LN2, W_FCB, b_fc, nullptr, H, M2, 3072, 768);

    // proj GEMM + bias + residual -> d_out (fp32)
    gemm_bt<1><<<(M2 / 256) * (768 / 128), 512, 0, stream>>>(
        H, W_PRB, b_proj, XNEW, (float*)d_out, M2, 768, 3072);
}

// Round 4
// 1668.896 us; speedup vs baseline: 1.2149x; 1.1161x over previous
//
#include <hip/hip_runtime.h>
#include <math.h>

// Problem constants
#define NT   197          // tokens
#define BB   256          // batch
#define CD   768          // channels
#define NHD  12           // heads
#define HD   64           // head dim
#define LTK  98           // kept tokens
#define NEWN 100          // L+2
#define M1   (NT*BB)      // 50432 rows
#define M2   (NEWN*BB)    // 25600 rows

typedef __attribute__((ext_vector_type(8))) short short8;
typedef __attribute__((ext_vector_type(4))) float float4v;

// ---------- bf16 helpers ----------
__device__ __forceinline__ short f2bf(float f) {
    unsigned int u = __float_as_uint(f);
    u = (u + 0x7fffu + ((u >> 16) & 1u)) >> 16;   // RNE
    return (short)u;
}

__device__ __forceinline__ void global_to_lds16(const short* g, short* l) {
    __builtin_amdgcn_global_load_lds(
        (__attribute__((address_space(1))) void*)(void*)g,
        (__attribute__((address_space(3))) void*)l, 16, 0, 0);
}

// ---------- fp32 -> bf16 convert ----------
__global__ __launch_bounds__(256) void cvt_bf16(const float* __restrict__ s,
                                                short* __restrict__ d, int n) {
    int i = blockIdx.x * 256 + threadIdx.x;
    if (i < n) d[i] = f2bf(s[i]);
}

// ---------- LayerNorm: fp32 in, bf16 out (+ optional stats) ----------
__global__ __launch_bounds__(256)
void ln_fwd(const float* __restrict__ x, const float* __restrict__ g,
            const float* __restrict__ bb, short* __restrict__ ob,
            float2* __restrict__ stats) {
    int row = blockIdx.x * 4 + (threadIdx.x >> 6);
    int lane = threadIdx.x & 63;
    const float* xr = x + (size_t)row * CD;
    float v[12]; float s = 0.f;
#pragma unroll
    for (int i = 0; i < 12; i++) { v[i] = xr[lane + i * 64]; s += v[i]; }
#pragma unroll
    for (int o = 32; o; o >>= 1) s += __shfl_xor(s, o);
    float mu = s * (1.f / 768.f);
    float s2 = 0.f;
#pragma unroll
    for (int i = 0; i < 12; i++) { float d = v[i] - mu; s2 += d * d; }
#pragma unroll
    for (int o = 32; o; o >>= 1) s2 += __shfl_xor(s2, o);
    float rsig = rsqrtf(s2 * (1.f / 768.f) + 1e-5f);
    if (stats != nullptr && lane == 0) stats[row] = make_float2(mu, rsig);
#pragma unroll
    for (int i = 0; i < 12; i++) {
        int c = lane + i * 64;
        ob[(size_t)row * CD + c] = f2bf((v[i] - mu) * rsig * g[c] + bb[c]);
    }
}

// ---------- BT GEMM, 256x128 tile, 512 thr / 8 waves (large-grid GEMMs) ----------
// EPI 0: bf16 out = acc + bias            (qkv)
// EPI 1: f32 out  = acc + bias + res[m,n] (out_proj)
// EPI 2: bf16 out = quickgelu(acc + bias) (fc)
template <int EPI>
__global__ __launch_bounds__(512)
void gemm_bt(const short* __restrict__ A, const short* __restrict__ Bw,
             const float* __restrict__ bias, const float* __restrict__ res,
             void* __restrict__ out, int M, int Nd, int K) {
    __shared__ short As[256 * 32];
    __shared__ short Bs[128 * 32];
    const int tid = threadIdx.x;

    const int mTiles = M >> 8, nTiles = Nd >> 7;
    const int GM = 8;
    int per = GM * nTiles;
    int grp = blockIdx.x / per;
    int rem = blockIdx.x - grp * per;
    int gm = mTiles - grp * GM; if (gm > GM) gm = GM;
    int mt = grp * GM + rem % gm;
    int nt = rem / gm;
    const int m0 = mt * 256, n0 = nt * 128;

    const int wave = tid >> 6, lane = tid & 63;
    const int wm = wave >> 1, wn = wave & 1;

    float4v acc[4][4];
#pragma unroll
    for (int a = 0; a < 4; a++)
#pragma unroll
        for (int b = 0; b < 4; b++) acc[a][b] = (float4v){0.f, 0.f, 0.f, 0.f};

    const int r = lane & 15, q = lane >> 4;

    for (int k0 = 0; k0 < K; k0 += 32) {
#pragma unroll
        for (int i = 0; i < 2; i++) {
            int id = (wave * 2 + i) * 64 + lane;
            int row = id >> 2, cpos = id & 3;
            int csrc = cpos ^ ((row >> 1) & 3);
            global_to_lds16(A + (size_t)(m0 + row) * K + k0 + csrc * 8,
                            As + (wave * 2 + i) * 512);
        }
        {
            int id = wave * 64 + lane;
            int row = id >> 2, cpos = id & 3;
            int csrc = cpos ^ ((row >> 1) & 3);
            global_to_lds16(Bw + (size_t)(n0 + row) * K + k0 + csrc * 8,
                            Bs + wave * 512);
        }
        __syncthreads();
        short8 af[4], bf[4];
#pragma unroll
        for (int mi = 0; mi < 4; mi++) {
            int row = wm * 64 + mi * 16 + r;
            int cp = q ^ ((row >> 1) & 3);
            af[mi] = *(const short8*)(As + row * 32 + cp * 8);
        }
#pragma unroll
        for (int ni = 0; ni < 4; ni++) {
            int row = wn * 64 + ni * 16 + r;
            int cp = q ^ ((row >> 1) & 3);
            bf[ni] = *(const short8*)(Bs + row * 32 + cp * 8);
        }
#pragma unroll
        for (int mi = 0; mi < 4; mi++)
#pragma unroll
            for (int ni = 0; ni < 4; ni++)
                acc[mi][ni] = __builtin_amdgcn_mfma_f32_16x16x32_bf16(
                    af[mi], bf[ni], acc[mi][ni], 0, 0, 0);
        __syncthreads();
    }

#pragma unroll
    for (int ni = 0; ni < 4; ni++) {
        int col = n0 + wn * 64 + ni * 16 + r;
        float bv = bias[col];
#pragma unroll
        for (int mi = 0; mi < 4; mi++) {
#pragma unroll
            for (int r2 = 0; r2 < 4; r2++) {
                int row = m0 + wm * 64 + mi * 16 + q * 4 + r2;
                size_t off = (size_t)row * Nd + col;
                float v = acc[mi][ni][r2] + bv;
                if (EPI == 0) {
                    ((short*)out)[off] = f2bf(v);
                } else if (EPI == 1) {
                    ((float*)out)[off] = v + res[off];
                } else {
                    float gel = v / (1.f + __expf(-1.702f * v));
                    ((short*)out)[off] = f2bf(gel);
                }
            }
        }
    }
}

// ---------- BT GEMM, 128x128 tile, 256 thr / 4 waves (grid-starved GEMMs) ----------
template <int EPI>
__global__ __launch_bounds__(256)
void gemm_bt128(const short* __restrict__ A, const short* __restrict__ Bw,
                const float* __restrict__ bias, const float* __restrict__ res,
                void* __restrict__ out, int M, int Nd, int K) {
    __shared__ short As[128 * 32];
    __shared__ short Bs[128 * 32];
    const int tid = threadIdx.x;

    const int mTiles = M >> 7, nTiles = Nd >> 7;
    const int GM = 8;
    int per = GM * nTiles;
    int grp = blockIdx.x / per;
    int rem = blockIdx.x - grp * per;
    int gm = mTiles - grp * GM; if (gm > GM) gm = GM;
    int mt = grp * GM + rem % gm;
    int nt = rem / gm;
    const int m0 = mt * 128, n0 = nt * 128;

    const int wave = tid >> 6, lane = tid & 63;
    const int wm = wave >> 1, wn = wave & 1;

    float4v acc[4][4];
#pragma unroll
    for (int a = 0; a < 4; a++)
#pragma unroll
        for (int b = 0; b < 4; b++) acc[a][b] = (float4v){0.f, 0.f, 0.f, 0.f};

    const int r = lane & 15, q = lane >> 4;

    for (int k0 = 0; k0 < K; k0 += 32) {
#pragma unroll
        for (int i = 0; i < 2; i++) {
            int id = (wave * 2 + i) * 64 + lane;
            int row = id >> 2, cpos = id & 3;
            int csrc = cpos ^ ((row >> 1) & 3);
            global_to_lds16(A + (size_t)(m0 + row) * K + k0 + csrc * 8,
                            As + (wave * 2 + i) * 512);
            global_to_lds16(Bw + (size_t)(n0 + row) * K + k0 + csrc * 8,
                            Bs + (wave * 2 + i) * 512);
        }
        __syncthreads();
        short8 af[4], bf[4];
#pragma unroll
        for (int mi = 0; mi < 4; mi++) {
            int row = wm * 64 + mi * 16 + r;
            int cp = q ^ ((row >> 1) & 3);
            af[mi] = *(const short8*)(As + row * 32 + cp * 8);
        }
#pragma unroll
        for (int ni = 0; ni < 4; ni++) {
            int row = wn * 64 + ni * 16 + r;
            int cp = q ^ ((row >> 1) & 3);
            bf[ni] = *(const short8*)(Bs + row * 32 + cp * 8);
        }
#pragma unroll
        for (int mi = 0; mi < 4; mi++)
#pragma unroll
            for (int ni = 0; ni < 4; ni++)
                acc[mi][ni] = __builtin_amdgcn_mfma_f32_16x16x32_bf16(
                    af[mi], bf[ni], acc[mi][ni], 0, 0, 0);
        __syncthreads();
    }

#pragma unroll
    for (int ni = 0; ni < 4; ni++) {
        int col = n0 + wn * 64 + ni * 16 + r;
        float bv = bias[col];
#pragma unroll
        for (int mi = 0; mi < 4; mi++) {
#pragma unroll
            for (int r2 = 0; r2 < 4; r2++) {
                int row = m0 + wm * 64 + mi * 16 + q * 4 + r2;
                size_t off = (size_t)row * Nd + col;
                float v = acc[mi][ni][r2] + bv;
                if (EPI == 0) {
                    ((short*)out)[off] = f2bf(v);
                } else if (EPI == 1) {
                    ((float*)out)[off] = v + res[off];
                } else {
                    float gel = v / (1.f + __expf(-1.702f * v));
                    ((short*)out)[off] = f2bf(gel);
                }
            }
        }
    }
}

// ---------- fused attention, one workgroup per (b,h), 7 waves ----------
__global__ __launch_bounds__(448)
void attn_kernel(const short* __restrict__ qkv, short* __restrict__ o) {
    __shared__ short Ks[224 * 72];
    __shared__ short Vt[64 * 232];
    __shared__ short Ps[7 * 16 * 232];

    const int b = blockIdx.x / NHD, h = blockIdx.x % NHD;
    const int tid = threadIdx.x;
    const int wave = tid >> 6, lane = tid & 63;

#pragma unroll
    for (int i = 0; i < 4; i++) {
        int id = tid + 448 * i;
        int n = id >> 3, ch = id & 7;
        uint4 val = {0u, 0u, 0u, 0u};
        if (n < NT)
            val = *(const uint4*)(qkv + ((size_t)(n * BB + b) * 2304 + 768 + h * 64 + ch * 8));
        *(uint4*)(&Ks[n * 72 + ch * 8]) = val;
    }
#pragma unroll
    for (int rr = 0; rr < 8; rr++) {
        int p = (tid >> 5) + rr * 14;
        int dl = tid & 31;
        int n0p = 2 * p;
#pragma unroll
        for (int di = 0; di < 2; di++) {
            int d = dl + 32 * di;
            unsigned int pack = 0;
            if (n0p < NT)
                pack |= (unsigned int)*(const unsigned short*)(qkv +
                    ((size_t)(n0p * BB + b) * 2304 + 1536 + h * 64 + d));
            if (n0p + 1 < NT)
                pack |= ((unsigned int)*(const unsigned short*)(qkv +
                    ((size_t)((n0p + 1) * BB + b) * 2304 + 1536 + h * 64 + d))) << 16;
            *(unsigned int*)(&Vt[d * 232 + n0p]) = pack;
        }
    }
    __syncthreads();

    short* Ps_w = Ps + wave * 16 * 232;
    const int cl = lane & 15, qg = lane >> 4;

    for (int rep = 0; rep < 2; rep++) {
        int qt = wave + rep * 7;
        int q0 = qt * 16;
        int m = q0 + cl; int mrow = (m < NT) ? m : (NT - 1);
        short8 qf[2];
#pragma unroll
        for (int kk = 0; kk < 2; kk++)
            qf[kk] = *(const short8*)(qkv + ((size_t)(mrow * BB + b) * 2304 +
                                             h * 64 + kk * 32 + qg * 8));
        float4v sacc[14];
#pragma unroll
        for (int nt = 0; nt < 14; nt++) sacc[nt] = (float4v){0.f, 0.f, 0.f, 0.f};
#pragma unroll
        for (int kk = 0; kk < 2; kk++) {
#pragma unroll
            for (int nt = 0; nt < 14; nt++) {
                short8 kf = *(const short8*)(&Ks[(nt * 16 + cl) * 72 + kk * 32 + qg * 8]);
                sacc[nt] = __builtin_amdgcn_mfma_f32_16x16x32_bf16(qf[kk], kf, sacc[nt], 0, 0, 0);
            }
        }
        float mx[4] = {-1e30f, -1e30f, -1e30f, -1e30f};
#pragma unroll
        for (int nt = 0; nt < 14; nt++) {
            int col = nt * 16 + cl;
            bool valid = col < NT;
#pragma unroll
            for (int r2 = 0; r2 < 4; r2++) {
                if (!valid) sacc[nt][r2] = -1e30f;
                mx[r2] = fmaxf(mx[r2], sacc[nt][r2]);
            }
        }
#pragma unroll
        for (int o2 = 1; o2 < 16; o2 <<= 1)
#pragma unroll
            for (int r2 = 0; r2 < 4; r2++) mx[r2] = fmaxf(mx[r2], __shfl_xor(mx[r2], o2));
        float sm[4] = {0.f, 0.f, 0.f, 0.f};
#pragma unroll
        for (int nt = 0; nt < 14; nt++)
#pragma unroll
            for (int r2 = 0; r2 < 4; r2++) {
                float pv = __expf((sacc[nt][r2] - mx[r2]) * 0.125f);
                sacc[nt][r2] = pv; sm[r2] += pv;
            }
#pragma unroll
        for (int o2 = 1; o2 < 16; o2 <<= 1)
#pragma unroll
            for (int r2 = 0; r2 < 4; r2++) sm[r2] += __shfl_xor(sm[r2], o2);
        float inv[4];
#pragma unroll
        for (int r2 = 0; r2 < 4; r2++) inv[r2] = 1.f / sm[r2];
#pragma unroll
        for (int nt = 0; nt < 14; nt++) {
            int col = nt * 16 + cl;
#pragma unroll
            for (int r2 = 0; r2 < 4; r2++)
                Ps_w[(qg * 4 + r2) * 232 + col] = f2bf(sacc[nt][r2] * inv[r2]);
        }
        __syncthreads();
        float4v oacc[4];
#pragma unroll
        for (int dt = 0; dt < 4; dt++) oacc[dt] = (float4v){0.f, 0.f, 0.f, 0.f};
#pragma unroll
        for (int kk = 0; kk < 7; kk++) {
            short8 pf = *(const short8*)(&Ps_w[cl * 232 + kk * 32 + qg * 8]);
#pragma unroll
            for (int dt = 0; dt < 4; dt++) {
                short8 vf = *(const short8*)(&Vt[(dt * 16 + cl) * 232 + kk * 32 + qg * 8]);
                oacc[dt] = __builtin_amdgcn_mfma_f32_16x16x32_bf16(pf, vf, oacc[dt], 0, 0, 0);
            }
        }
#pragma unroll
        for (int dt = 0; dt < 4; dt++)
#pragma unroll
            for (int r2 = 0; r2 < 4; r2++) {
                int qrow = q0 + qg * 4 + r2;
                if (qrow < NT)
                    o[((size_t)qrow * BB + b) * CD + h * 64 + dt * 16 + cl] = f2bf(oacc[dt][r2]);
            }
        __syncthreads();
    }
}

// ---------- fp32 ranking path (rewritten as tiled fp32 GEMMs) ----------

// LN of CLS rows -> LNC[256][768] fp32
__global__ __launch_bounds__(256)
void lnc_kernel(const float* __restrict__ x, const float2* __restrict__ stats,
                const float* __restrict__ g, const float* __restrict__ bln,
                float* __restrict__ lnc) {
    int b = blockIdx.x;
    float2 st = stats[b];
#pragma unroll
    for (int i = 0; i < 3; i++) {
        int c = threadIdx.x + i * 256;
        lnc[(size_t)b * CD + c] = (x[(size_t)b * CD + c] - st.x) * st.y * g[c] + bln[c];
    }
}

// C[m][n] = sum_k A[m][k]*B[n][k] + bias[n]   (fp32, 64x64 tile, BK=32)
__global__ __launch_bounds__(256)
void gemm32_nt(const float* __restrict__ A, const float* __restrict__ B,
               const float* __restrict__ bias, float* __restrict__ C,
               int lda, int ldb, int ldc) {
    __shared__ float As[32][65];
    __shared__ float Bs[32][65];
    const int tid = threadIdx.x;
    const int m0 = blockIdx.x * 64, n0 = blockIdx.y * 64;
    const int tx = tid & 15, ty = tid >> 4;
    float acc[4][4] = {};
    const int K = 768;
    for (int k0 = 0; k0 < K; k0 += 32) {
#pragma unroll
        for (int i = 0; i < 8; i++) {
            int idx = i * 256 + tid;
            int rr = idx >> 5, kc = idx & 31;
            As[kc][rr] = A[(size_t)(m0 + rr) * lda + k0 + kc];
            Bs[kc][rr] = B[(size_t)(n0 + rr) * ldb + k0 + kc];
        }
        __syncthreads();
#pragma unroll
        for (int kk = 0; kk < 32; kk++) {
            float a_[4], b_[4];
#pragma unroll
            for (int i = 0; i < 4; i++) a_[i] = As[kk][ty * 4 + i];
#pragma unroll
            for (int j = 0; j < 4; j++) b_[j] = Bs[kk][tx * 4 + j];
#pragma unroll
            for (int i = 0; i < 4; i++)
#pragma unroll
                for (int j = 0; j < 4; j++) acc[i][j] += a_[i] * b_[j];
        }
        __syncthreads();
    }
#pragma unroll
    for (int i = 0; i < 4; i++)
#pragma unroll
        for (int j = 0; j < 4; j++) {
            int n = n0 + tx * 4 + j;
            C[(size_t)(m0 + ty * 4 + i) * ldc + n] = acc[i][j] + bias[n];
        }
}

// C[m][n] += A[m][k]*B[k][n], K=64 (fp32, 64x64 tile, BK=32); per-head via blockIdx.z
__global__ __launch_bounds__(256)
void gemm32_nn_u(const float* __restrict__ QC, const float* __restrict__ W,
                 float* __restrict__ U) {
    __shared__ float As[32][65];
    __shared__ float Bs[32][65];
    const int tid = threadIdx.x;
    const int m0 = blockIdx.x * 64, n0 = blockIdx.y * 64, h = blockIdx.z;
    const float* A = QC + h * 64;                       // lda 768, K=64
    const float* B = W + (size_t)(CD + h * 64) * CD;    // ldb 768
    const int tx = tid & 15, ty = tid >> 4;
    float acc[4][4] = {};
    for (int k0 = 0; k0 < 64; k0 += 32) {
#pragma unroll
        for (int i = 0; i < 8; i++) {
            int idx = i * 256 + tid;
            int mr = idx >> 5, kc = idx & 31;
            As[kc][mr] = A[(size_t)(m0 + mr) * CD + k0 + kc];
            int kr = idx >> 6, nc = idx & 63;
            if (i < 8) { /* 32*64 = 2048 elements, same count */ }
            Bs[kr][nc] = B[(size_t)(k0 + kr) * CD + n0 + nc];
        }
        __syncthreads();
#pragma unroll
        for (int kk = 0; kk < 32; kk++) {
            float a_[4], b_[4];
#pragma unroll
            for (int i = 0; i < 4; i++) a_[i] = As[kk][ty * 4 + i];
#pragma unroll
            for (int j = 0; j < 4; j++) b_[j] = Bs[kk][tx * 4 + j];
#pragma unroll
            for (int i = 0; i < 4; i++)
#pragma unroll
                for (int j = 0; j < 4; j++) acc[i][j] += a_[i] * b_[j];
        }
        __syncthreads();
    }
#pragma unroll
    for (int i = 0; i < 4; i++)
#pragma unroll
        for (int j = 0; j < 4; j++) {
            int b = m0 + ty * 4 + i, c = n0 + tx * 4 + j;
            U[((size_t)b * NHD + h) * CD + c] = acc[i][j];
        }
}

// tq[b,h] = sum_d QC[b][h*64+d] * pb[768+h*64+d]
__global__ __launch_bounds__(256)
void tq_kernel(const float* __restrict__ QC, const float* __restrict__ pb,
               float* __restrict__ tq) {
    int h = blockIdx.x, b = threadIdx.x;
    float acc = 0.f;
#pragma unroll
    for (int d = 0; d < 64; d++)
        acc += QC[(size_t)b * CD + h * 64 + d] * pb[CD + h * 64 + d];
    tq[b * NHD + h] = acc;
}

__global__ __launch_bounds__(256)
void scores_kernel(const float* __restrict__ x, const float2* __restrict__ stats,
                   const float* __restrict__ g, const float* __restrict__ bln,
                   const float* __restrict__ u, const float* __restrict__ tq,
                   float* __restrict__ scores) {
    int bi = blockIdx.x; int b = bi / NT, n = bi % NT;
    __shared__ float ln[CD];
    int row = n * BB + b;
    float2 st = stats[row];
    for (int c = threadIdx.x; c < CD; c += 256)
        ln[c] = (x[(size_t)row * CD + c] - st.x) * st.y * g[c] + bln[c];
    __syncthreads();
    int wave = threadIdx.x >> 6, lane = threadIdx.x & 63;
    for (int h = wave; h < NHD; h += 4) {
        const float* ub = u + ((size_t)b * NHD + h) * CD;
        float acc = 0.f;
#pragma unroll
        for (int i = 0; i < 12; i++) acc += ub[lane + i * 64] * ln[lane + i * 64];
#pragma unroll
        for (int o2 = 32; o2; o2 >>= 1) acc += __shfl_xor(acc, o2);
        if (lane == 0)
            scores[((size_t)b * NHD + h) * NT + n] = (acc + tq[b * NHD + h]) * 0.125f;
    }
}

__global__ __launch_bounds__(256)
void softmax_avg(const float* __restrict__ scores, float* __restrict__ cls_attn) {
    int b = blockIdx.x;
    __shared__ float p[NHD][NT];
    int wave = threadIdx.x >> 6, lane = threadIdx.x & 63;
    for (int h = wave; h < NHD; h += 4) {
        const float* s = scores + ((size_t)b * NHD + h) * NT;
        float v[4]; float mx = -1e30f;
#pragma unroll
        for (int i = 0; i < 4; i++) {
            int n = lane + i * 64;
            v[i] = (n < NT) ? s[n] : -1e30f;
            mx = fmaxf(mx, v[i]);
        }
#pragma unroll
        for (int o2 = 32; o2; o2 >>= 1) mx = fmaxf(mx, __shfl_xor(mx, o2));
        float sum = 0.f;
#pragma unroll
        for (int i = 0; i < 4; i++) {
            int n = lane + i * 64;
            v[i] = (n < NT) ? __expf(v[i] - mx) : 0.f;
            sum += v[i];
        }
#pragma unroll
        for (int o2 = 32; o2; o2 >>= 1) sum += __shfl_xor(sum, o2);
        float inv = 1.f / sum;
#pragma unroll
        for (int i = 0; i < 4; i++) {
            int n = lane + i * 64;
            if (n < NT) p[h][n] = v[i] * inv;
        }
    }
    __syncthreads();
    for (int n = 1 + (int)threadIdx.x; n < NT; n += 256) {
        float a = 0.f;
#pragma unroll
        for (int h = 0; h < NHD; h++) a += p[h][n];
        cls_attn[(size_t)b * (NT - 1) + n - 1] = a * (1.f / 12.f);
    }
}

__global__ __launch_bounds__(256)
void topk_kernel(const float* __restrict__ cls_attn, int* __restrict__ idx,
                 int* __restrict__ cidx, float* __restrict__ cw) {
    int b = blockIdx.x, t = threadIdx.x;
    __shared__ float kv[256];
    __shared__ int ki[256];
    __shared__ int pos[256];
    __shared__ unsigned char mem[256];
    float myv = (t < NT - 1) ? cls_attn[(size_t)b * (NT - 1) + t] : -INFINITY;
    kv[t] = myv; ki[t] = t;
    __syncthreads();
    for (int k = 2; k <= 256; k <<= 1) {
        for (int j = k >> 1; j > 0; j >>= 1) {
            int ixj = t ^ j;
            if (ixj > t) {
                bool up = ((t & k) == 0);
                float va = kv[t], vb = kv[ixj];
                int ia = ki[t], ib = ki[ixj];
                bool beforeAB = (va > vb) || (va == vb && ia < ib);
                bool sw = up ? !beforeAB : beforeAB;
                if (sw) { kv[t] = vb; kv[ixj] = va; ki[t] = ib; ki[ixj] = ia; }
            }
            __syncthreads();
        }
    }
    if (t < LTK) idx[(size_t)b * LTK + t] = ki[t];
    mem[t] = 0;
    __syncthreads();
    if (t < LTK) mem[ki[t]] = 1;
    __syncthreads();
    int f = (t < NT - 1) ? (1 - (int)mem[t]) : 0;
    pos[t] = f;
    __syncthreads();
    for (int o2 = 1; o2 < 256; o2 <<= 1) {
        int add = (t >= o2) ? pos[t - o2] : 0;
        __syncthreads();
        pos[t] += add;
        __syncthreads();
    }
    if (f) {
        int p = pos[t] - 1;
        cidx[(size_t)b * LTK + p] = t;
        cw[(size_t)b * LTK + p] = myv;
    }
}

__global__ __launch_bounds__(256)
void assemble(const float* __restrict__ x1, const int* __restrict__ idx,
              const int* __restrict__ cidx, const float* __restrict__ cw,
              float* __restrict__ xnew) {
    int b = blockIdx.x;
    for (int c = threadIdx.x; c < CD; c += 256)
        xnew[(size_t)b * CD + c] = x1[(size_t)b * CD + c];
    for (int j = 0; j < LTK; j++) {
        int ns = idx[b * LTK + j] + 1;
        for (int c = threadIdx.x; c < CD; c += 256)
            xnew[((size_t)(1 + j) * BB + b) * CD + c] = x1[((size_t)ns * BB + b) * CD + c];
    }
    float acc[3] = {0.f, 0.f, 0.f};
    for (int m = 0; m < LTK; m++) {
        int ns = cidx[b * LTK + m] + 1;
        float w = cw[b * LTK + m];
#pragma unroll
        for (int i = 0; i < 3; i++)
            acc[i] += w * x1[((size_t)ns * BB + b) * CD + threadIdx.x + i * 256];
    }
#pragma unroll
    for (int i = 0; i < 3; i++)
        xnew[((size_t)99 * BB + b) * CD + threadIdx.x + i * 256] = acc[i];
}

__global__ __launch_bounds__(256) void sentinel_fill(float* __restrict__ p, int n) {
    int i = blockIdx.x * 256 + threadIdx.x;
    if (i < n) p[i] = 12345.0f;
}

// ---------- workspace layout ----------
#define OFF_WQKVB 0ULL
#define OFF_WOB   3538944ULL
#define OFF_WFCB  4718592ULL
#define OFF_WPRB  9437184ULL
#define OFF_STATS 14155776ULL
#define OFF_LN1   14559232ULL            /* bf16; O aliases this after qkv-GEMM */
#define OFF_O     OFF_LN1
#define OFF_QKV   92022784ULL            /* bf16; H aliases this after attn */
#define OFF_H     OFF_QKV
#define OFF_X1    324413440ULL           /* fp32; LNC/QC alias head of this during ranking */
#define OFF_LNC   OFF_X1
#define OFF_QC    (OFF_X1 + 786432ULL)
#define OFF_U     479340544ULL
#define OFF_TQ    488777728ULL
#define OFF_SC    488790016ULL
#define OFF_CA    491210752ULL
#define OFF_IDX   491411456ULL
#define OFF_CIDX  491511808ULL
#define OFF_CW    491612160ULL
#define OFF_XNEW  491712512ULL
#define OFF_LN2   570355712ULL
#define WS_NEED   609677312ULL

extern "C" void kernel_launch(void* const* d_in, const int* in_sizes, int n_in,
                              void* d_out, int out_size, void* d_ws, size_t ws_size,
                              hipStream_t stream) {
    const float* x      = (const float*)d_in[0];
    const float* ln1_g  = (const float*)d_in[1];
    const float* ln1_b  = (const float*)d_in[2];
    const float* w_qkv  = (const float*)d_in[3];
    const float* b_qkv  = (const float*)d_in[4];
    const float* w_o    = (const float*)d_in[5];
    const float* b_o    = (const float*)d_in[6];
    const float* ln2_g  = (const float*)d_in[7];
    const float* ln2_b  = (const float*)d_in[8];
    const float* w_fc   = (const float*)d_in[9];
    const float* b_fc   = (const float*)d_in[10];
    const float* w_proj = (const float*)d_in[11];
    const float* b_proj = (const float*)d_in[12];

    if (ws_size < WS_NEED) {
        sentinel_fill<<<(out_size + 255) / 256, 256, 0, stream>>>((float*)d_out, out_size);
        return;
    }

    char* ws = (char*)d_ws;
    short*  W_QKVB = (short*)(ws + OFF_WQKVB);
    short*  W_OB   = (short*)(ws + OFF_WOB);
    short*  W_FCB  = (short*)(ws + OFF_WFCB);
    short*  W_PRB  = (short*)(ws + OFF_WPRB);
    float2* STATS  = (float2*)(ws + OFF_STATS);
    short*  LN1    = (short*)(ws + OFF_LN1);
    short*  O      = (short*)(ws + OFF_O);
    short*  QKV    = (short*)(ws + OFF_QKV);
    short*  H      = (short*)(ws + OFF_H);
    float*  X1     = (float*)(ws + OFF_X1);
    float*  LNC    = (float*)(ws + OFF_LNC);
    float*  QC     = (float*)(ws + OFF_QC);
    float*  U      = (float*)(ws + OFF_U);
    float*  TQ     = (float*)(ws + OFF_TQ);
    float*  SC     = (float*)(ws + OFF_SC);
    float*  CA     = (float*)(ws + OFF_CA);
    int*    IDX    = (int*)(ws + OFF_IDX);
    int*    CIDX   = (int*)(ws + OFF_CIDX);
    float*  CW     = (float*)(ws + OFF_CW);
    float*  XNEW   = (float*)(ws + OFF_XNEW);
    short*  LN2    = (short*)(ws + OFF_LN2);

    // weights -> bf16
    cvt_bf16<<<(2304 * 768 + 255) / 256, 256, 0, stream>>>(w_qkv, W_QKVB, 2304 * 768);
    cvt_bf16<<<(768 * 768 + 255) / 256, 256, 0, stream>>>(w_o, W_OB, 768 * 768);
    cvt_bf16<<<(3072 * 768 + 255) / 256, 256, 0, stream>>>(w_fc, W_FCB, 3072 * 768);
    cvt_bf16<<<(768 * 3072 + 255) / 256, 256, 0, stream>>>(w_proj, W_PRB, 768 * 3072);

    // LN1 (bf16 out + stats for fp32 ranking replay)
    ln_fwd<<<M1 / 4, 256, 0, stream>>>(x, ln1_g, ln1_b, LN1, STATS);

    // qkv GEMM (bf16)
    gemm_bt<0><<<(M1 / 256) * (2304 / 128), 512, 0, stream>>>(
        LN1, W_QKVB, b_qkv, nullptr, QKV, M1, 2304, 768);

    // fused attention -> O (bf16)
    attn_kernel<<<BB * NHD, 448, 0, stream>>>(QKV, O);

    // fp32 ranking path: LNC -> QC -> U/TQ -> scores -> softmax/avg -> topk
    lnc_kernel<<<BB, 256, 0, stream>>>(x, STATS, ln1_g, ln1_b, LNC);
    gemm32_nt<<<dim3(BB / 64, CD / 64), 256, 0, stream>>>(
        LNC, w_qkv, b_qkv, QC, CD, CD, CD);
    gemm32_nn_u<<<dim3(BB / 64, CD / 64, NHD), 256, 0, stream>>>(QC, w_qkv, U);
    tq_kernel<<<NHD, 256, 0, stream>>>(QC, b_qkv, TQ);
    scores_kernel<<<BB * NT, 256, 0, stream>>>(x, STATS, ln1_g, ln1_b, U, TQ, SC);
    softmax_avg<<<BB, 256, 0, stream>>>(SC, CA);
    topk_kernel<<<BB, 256, 0, stream>>>(CA, IDX, CIDX, CW);

    // out_proj GEMM + residual -> x1 (fp32)  [must run AFTER ranking: X1 aliases LNC/QC]
    gemm_bt<1><<<(M1 / 256) * (768 / 128), 512, 0, stream>>>(
        O, W_OB, b_o, x, X1, M1, 768, 768);

    // token select/merge -> x_new (fp32)
    assemble<<<BB, 256, 0, stream>>>(X1, IDX, CIDX, CW, XNEW);

    // LN2 -> bf16
    ln_fwd<<<M2 / 4, 256, 0, stream>>>(XNEW, ln2_g, ln2_b, LN2, nullptr);

    // fc GEMM + quickGELU -> H (bf16)
    gemm_bt<2><<<(M2 / 256) * (3072 / 128), 512, 0, stream>>>(
        LN2, W_FCB, b_fc, nullptr, H, M2, 3072, 768);

    // proj GEMM + bias + residual -> d_out (fp32): grid-starved at 256-tile -> 128-tile
    gemm_bt128<1><<<(M2 / 128) * (768 / 128), 256, 0, stream>>>(
        H, W_PRB, b_proj, XNEW, (float*)d_out, M2, 768, 3072);
}